// Round 18
// baseline (342.998 us; speedup 1.0000x reference)
//
#include <hip/hip_runtime.h>
#include <math.h>

#define B_ 4
#define T_ 2048
#define D_ 256
#define H_ 4
#define DH_ 64
#define INNER_ 512
#define FFI_ 1024

typedef unsigned short u16;
typedef __bf16 bhalf;
typedef bhalf bhalf8 __attribute__((ext_vector_type(8)));
typedef float floatx4 __attribute__((ext_vector_type(4)));

__device__ __forceinline__ float lrelu(float x){ return x >= 0.f ? x : 0.3f * x; }

// native RTNE bf16 convert (v_cvt_pk_bf16_f32)
__device__ __forceinline__ u16 f2b(float f){
    __bf16 h = (__bf16)f;
    return __builtin_bit_cast(unsigned short, h);
}
__device__ __forceinline__ float b2f(u16 v){ return __uint_as_float((unsigned)v << 16); }

__device__ __forceinline__ void gload16(const void* g, void* l){
    __builtin_amdgcn_global_load_lds(
        (const __attribute__((address_space(1))) unsigned*)g,
        (__attribute__((address_space(3))) unsigned*)l, 16, 0, 0);
}

// ---- DPP 16-lane rotate-reduce (row_ror:1/2/4/8), pure VALU, no LDS pipe ----
__device__ __forceinline__ float dpp16_add(float x){
    int t;
    t = __builtin_amdgcn_update_dpp(0, __float_as_int(x), 0x121, 0xf, 0xf, false); x += __int_as_float(t);
    t = __builtin_amdgcn_update_dpp(0, __float_as_int(x), 0x122, 0xf, 0xf, false); x += __int_as_float(t);
    t = __builtin_amdgcn_update_dpp(0, __float_as_int(x), 0x124, 0xf, 0xf, false); x += __int_as_float(t);
    t = __builtin_amdgcn_update_dpp(0, __float_as_int(x), 0x128, 0xf, 0xf, false); x += __int_as_float(t);
    return x;
}
__device__ __forceinline__ float dpp16_max(float x){
    int t;
    t = __builtin_amdgcn_update_dpp(0, __float_as_int(x), 0x121, 0xf, 0xf, false); x = fmaxf(x, __int_as_float(t));
    t = __builtin_amdgcn_update_dpp(0, __float_as_int(x), 0x122, 0xf, 0xf, false); x = fmaxf(x, __int_as_float(t));
    t = __builtin_amdgcn_update_dpp(0, __float_as_int(x), 0x124, 0xf, 0xf, false); x = fmaxf(x, __int_as_float(t));
    t = __builtin_amdgcn_update_dpp(0, __float_as_int(x), 0x128, 0xf, 0xf, false); x = fmaxf(x, __int_as_float(t));
    return x;
}

// ------------- weight/activation cast kernels (float4-vectorized) -------------
__global__ __launch_bounds__(256) void cast4_kernel(
        const float* __restrict__ s0, u16* d0, int n0_,
        const float* __restrict__ s1, u16* d1, int n1_,
        const float* __restrict__ s2, u16* d2, int n2_,
        const float* __restrict__ s3, u16* d3, int n3_){
    int idx4 = (blockIdx.x * 256 + threadIdx.x) * 4;
    int y = blockIdx.y;
    const float* s = y==0 ? s0 : y==1 ? s1 : y==2 ? s2 : s3;
    u16* d        = y==0 ? d0 : y==1 ? d1 : y==2 ? d2 : d3;
    int n         = y==0 ? n0_ : y==1 ? n1_ : y==2 ? n2_ : n3_;
    if (idx4 < n){                       // n % 4 == 0 for all inputs
        float4 v = *(const float4*)(s + idx4);
        ushort4 o;
        o.x = f2b(v.x); o.y = f2b(v.y); o.z = f2b(v.z); o.w = f2b(v.w);
        *(ushort4*)(d + idx4) = o;
    }
}

// 256x256 transpose-cast via LDS tile (vT_kernel-proven pattern):
// d[n][k] = bf16(s[k][n]); coalesced float4 reads + float4 writes.
__global__ __launch_bounds__(256) void castT5_kernel(
        const float* __restrict__ s0, const float* __restrict__ s1,
        const float* __restrict__ s2, const float* __restrict__ s3,
        const float* __restrict__ s4,
        u16* d0, u16* d1, u16* d2, u16* d3, u16* d4){
    __shared__ u16 tile[64 * 68];
    int y = blockIdx.y;
    const float* s = y==0 ? s0 : y==1 ? s1 : y==2 ? s2 : y==3 ? s3 : s4;
    u16* d        = y==0 ? d0 : y==1 ? d1 : y==2 ? d2 : y==3 ? d3 : d4;
    int k0 = (blockIdx.x & 3) * 64, n0 = (blockIdx.x >> 2) * 64;
    int tid = threadIdx.x;
    // load: tile[k][n] <- bf16(s[k0+k][n0+n]), 4 f32 per thread pass
    for (int u = tid; u < 1024; u += 256){
        int r = u >> 4, c4 = (u & 15) * 4;
        float4 v = *(const float4*)(s + (size_t)(k0 + r) * 256 + n0 + c4);
        u16 o4[4];
        o4[0] = f2b(v.x); o4[1] = f2b(v.y); o4[2] = f2b(v.z); o4[3] = f2b(v.w);
        *(uint2*)&tile[r * 68 + c4] = *(uint2*)o4;
    }
    __syncthreads();
    // write: d[n0+n][k0+k] <- tile[k][n], 8 u16 per thread pass
    for (int u = tid; u < 512; u += 256){
        int n = u >> 3, k8 = (u & 7) * 8;
        u16 g[8];
        #pragma unroll
        for (int j = 0; j < 8; j++) g[j] = tile[(k8 + j) * 68 + n];
        *(float4*)(d + (size_t)(n0 + n) * 256 + k0 + k8) = *(float4*)g;
    }
}

__global__ __launch_bounds__(256) void castFF1_kernel(const float* __restrict__ s, u16* d){
    int idx = blockIdx.x * 256 + threadIdx.x;
    int n = idx / 768, rem = idx - n * 768;
    int kc = rem >> 8, c = rem & 255;
    d[idx] = f2b(s[(n * 256 + c) * 3 + kc]);
}

// ---------------- LayerNorm: one wave per 256-elem row ----------------
__global__ __launch_bounds__(256) void ln_kernel(const float* __restrict__ x,
        const float* __restrict__ g, const float* __restrict__ b,
        u16* __restrict__ out){
    int wave = threadIdx.x >> 6, lane = threadIdx.x & 63;
    int row = blockIdx.x * 4 + wave;
    size_t base = (size_t)row * D_ + lane * 4;
    float4 v = *(const float4*)(x + base);
    float s = v.x + v.y + v.z + v.w;
    #pragma unroll
    for (int mk = 1; mk < 64; mk <<= 1) s += __shfl_xor(s, mk, 64);
    float mean = s * (1.f / D_);
    float4 d = make_float4(v.x - mean, v.y - mean, v.z - mean, v.w - mean);
    float q = d.x*d.x + d.y*d.y + d.z*d.z + d.w*d.w;
    #pragma unroll
    for (int mk = 1; mk < 64; mk <<= 1) q += __shfl_xor(q, mk, 64);
    float rs = rsqrtf(q * (1.f / D_) + 1e-5f);
    float4 gg = *(const float4*)(g + lane * 4);
    float4 bb = *(const float4*)(b + lane * 4);
    ushort4 o;
    o.x = f2b(d.x * rs * gg.x + bb.x);
    o.y = f2b(d.y * rs * gg.y + bb.y);
    o.z = f2b(d.z * rs * gg.z + bb.z);
    o.w = f2b(d.w * rs * gg.w + bb.w);
    *(ushort4*)(out + base) = o;
}

// ===== bf16 MFMA GEMM, BK=64, XOR-swizzled LDS (conflict-free b128 reads) =====
// Wave tilings: 128x128 (4 waves, 64x64 each), 128x64 (4 waves, 32x64),
// 64x64 (4 waves, 32x32), 64x128 (4 waves, 32x64 each).
template<int BM, int BN, int AMODE, bool BIAS, bool ACT, bool RES, bool OUTBF>
__global__ __launch_bounds__(256) void gemm_bf(
        const u16* __restrict__ A, const u16* __restrict__ Bw,
        const float* __restrict__ bias, const float* __restrict__ res,
        void* __restrict__ C, int M, int N, int K, float alpha,
        const u16* __restrict__ zbuf){
    __shared__ __align__(16) u16 As[BM * 64];
    __shared__ __align__(16) u16 Bs[BN * 64];
    const int tid = threadIdx.x;
    const int lane = tid & 63, w = tid >> 6;
    const int ln15 = lane & 15, quad = lane >> 4;
    const int lsw = ln15 & 7;
    const int m0 = blockIdx.y * BM, n0 = blockIdx.x * BN;
    const int srow8 = lane >> 3;                 // row within 8-row stage chunk
    const int swzc  = ((lane & 7) ^ srow8) * 8;  // pre-swizzled source col (u16)
    const bool M64N128 = (BM == 64 && BN == 128);
    const int MT = (BM == 64) ? 2 : ((BN == 128) ? 4 : 2);
    const int NT = M64N128 ? 4 : ((BM == 64) ? 2 : 4);
    const int wm = M64N128 ? (w & 1) : ((BM == 64 || BN == 128) ? (w >> 1) : w);
    const int wn = M64N128 ? (w >> 1) : ((BM == 64 || BN == 128) ? (w & 1) : 0);
    const int mbase = M64N128 ? wm * 32
                     : ((BM == 64) ? wm * 32 : ((BN == 128) ? wm * 64 : w * 32));
    const int nbase = M64N128 ? wn * 64
                     : ((BM == 64) ? wn * 32 : ((BN == 128) ? wn * 64 : 0));
    const int JA = BM / 32;                      // A stage gloads per wave
    const int JB = BN / 32;

    floatx4 acc[4][4];
    #pragma unroll
    for (int i = 0; i < 4; i++)
        #pragma unroll
        for (int j = 0; j < 4; j++)
            acc[i][j] = (floatx4){0.f, 0.f, 0.f, 0.f};

    for (int k0 = 0; k0 < K; k0 += 64){
        __syncthreads();
        #pragma unroll
        for (int j = 0; j < JA; j++){
            int mrow = m0 + w * (BM / 4) + j * 8 + srow8;
            const u16* ga;
            if (AMODE == 0){
                ga = A + (size_t)mrow * K + k0 + swzc;
            } else {
                int bb = mrow >> 11, t = mrow & (T_ - 1);
                int kc = k0 >> 8;
                int c = (k0 & 255) + swzc;        // swzc<64, k0%64==0 -> no 256-cross
                int t2 = t + kc - 1;
                ga = ((unsigned)t2 < (unsigned)T_)
                     ? A + ((size_t)(bb * T_ + t2)) * D_ + c : zbuf;
            }
            gload16(ga, &As[(w * (BM / 4) + j * 8) * 64]);
        }
        #pragma unroll
        for (int j = 0; j < JB; j++){
            const u16* gb = Bw + (size_t)(n0 + w * (BN / 4) + j * 8 + srow8) * K + k0 + swzc;
            gload16(gb, &Bs[(w * (BN / 4) + j * 8) * 64]);
        }
        __syncthreads();
        #pragma unroll
        for (int ks = 0; ks < 2; ks++){
            const int rc = (((ks << 2) + quad) ^ lsw) * 8;
            bhalf8 af[4], bfr[4];
            #pragma unroll
            for (int mi = 0; mi < MT; mi++)
                af[mi] = *(const bhalf8*)&As[(mbase + mi * 16 + ln15) * 64 + rc];
            #pragma unroll
            for (int ni = 0; ni < NT; ni++)
                bfr[ni] = *(const bhalf8*)&Bs[(nbase + ni * 16 + ln15) * 64 + rc];
            #pragma unroll
            for (int mi = 0; mi < MT; mi++)
                #pragma unroll
                for (int ni = 0; ni < NT; ni++)
                    acc[mi][ni] = __builtin_amdgcn_mfma_f32_16x16x32_bf16(
                        af[mi], bfr[ni], acc[mi][ni], 0, 0, 0);
        }
    }
    #pragma unroll
    for (int mi = 0; mi < MT; mi++){
        #pragma unroll
        for (int ni = 0; ni < NT; ni++){
            int n = n0 + nbase + ni * 16 + ln15;
            float bv = BIAS ? bias[n] : 0.f;
            #pragma unroll
            for (int r = 0; r < 4; r++){
                int m = m0 + mbase + mi * 16 + quad * 4 + r;
                float val = acc[mi][ni][r] + bv;
                if (ACT) val = lrelu(val);
                if (RES) val = res[(size_t)m * N + n] + alpha * val;
                if (OUTBF) ((u16*)C)[(size_t)m * N + n] = f2b(val);
                else       ((float*)C)[(size_t)m * N + n] = val;
            }
        }
    }
}

// ---------------- V transpose: qkv[:,512+..] [B*T][768] -> vbT [B][256][T] ----------------
__global__ __launch_bounds__(256) void vT_kernel(const u16* __restrict__ qkv, u16* __restrict__ vbT){
    __shared__ u16 tile[64 * 68];
    int t0 = blockIdx.x * 64, d0 = blockIdx.y * 64, b = blockIdx.z;
    int tid = threadIdx.x;
    for (int u = tid; u < 512; u += 256){
        int r = u >> 3, c8 = (u & 7) * 8;
        *(float4*)&tile[r * 68 + c8] =
            *(const float4*)(qkv + ((size_t)(b * T_ + t0 + r)) * 768 + 512 + d0 + c8);
    }
    __syncthreads();
    for (int u = tid; u < 512; u += 256){
        int d = u >> 3, t8 = (u & 7) * 8;
        u16 g[8];
        #pragma unroll
        for (int j = 0; j < 8; j++) g[j] = tile[(t8 + j) * 68 + d];
        *(float4*)(vbT + ((size_t)(b * 256 + d0 + d)) * T_ + t0 + t8) = *(float4*)g;
    }
}

// ========== 8-wave QBLK=128 flash attention, gload_lds staging + XOR swizzle ==========
// (round-4/9/10/11/12/15/17 HW-verified: ~89-94 us, VGPR 64, bank conflicts 0)
__global__ __launch_bounds__(512) void attn11_kernel(
        const u16* __restrict__ qkv, const u16* __restrict__ vbT,
        const u16* __restrict__ posb,
        const float* __restrict__ ub, const float* __restrict__ vbias,
        float* __restrict__ Op, float* __restrict__ ml,
        const u16* __restrict__ zbuf)
{
    __shared__ __align__(16) u16 Ks[64 * 64];
    __shared__ __align__(16) u16 Vs[64 * 64];
    __shared__ __align__(16) u16 Pos[192 * 64];
    __shared__ __align__(16) u16 Pb[8 * 16 * 90];

    const int tid = threadIdx.x;
    const int lane = tid & 63, w = tid >> 6;
    const int ln15 = lane & 15, quad = lane >> 4;
    const int lsw = ln15 & 7;                 // read-side XOR key (row&7 == ln15&7)

    // XCD-locality swizzle: 512 = 8 xcd * 2 bh * 2 z * 16 t-blocks (bijective)
    int wgid = blockIdx.x + 16 * (blockIdx.y + 16 * blockIdx.z);
    int xcd = wgid & 7, idx = wgid >> 3;               // idx in [0,64)
    const int bh = xcd * 2 + (idx >> 5);
    const int z  = (idx >> 4) & 1;
    const int t0 = (idx & 15) * 128;
    const int b = bh >> 2, h = bh & 3;

    const u16* qg  = qkv + (size_t)b * T_ * 768 + h * DH_;
    const u16* kg  = qkv + (size_t)b * T_ * 768 + 256 + h * DH_;
    const u16* vtg = vbT + ((size_t)(b * 256 + h * DH_)) * T_;
    const u16* pg  = posb + h * DH_;

    // staging geometry: wave w stages rows [w*8, w*8+8); lane -> (row, chunk)
    const int srow8 = lane >> 3;              // row within the wave's 8-row strip
    const int swz8  = (lane & 7) ^ srow8;     // pre-swizzled source chunk * 8 u16
    const int srowg = w * 8 + srow8;          // row within 64-row tile

    // ---- register Q fragments (wave w owns q-rows t0+w*16 .. +15) ----
    bhalf8 quf[2], qvf0[2], qvf1[2];
    {
        int qrow = t0 + w * 16 + ln15;
        #pragma unroll
        for (int ks = 0; ks < 2; ks++){
            int dof = ks * 32 + quad * 8;
            u16 q8[8];
            *(float4*)q8 = *(const float4*)(qg + (size_t)qrow * 768 + dof);
            u16 q8n[8] = {0,0,0,0,0,0,0,0};
            if (qrow + 1 < T_)
                *(float4*)q8n = *(const float4*)(qg + (size_t)(qrow + 1) * 768 + dof);
            u16 a[8], c0[8], c1[8];
            #pragma unroll
            for (int j = 0; j < 8; j++){
                float uu = ub[h * DH_ + dof + j];
                float vv = vbias[h * DH_ + dof + j];
                float qf = b2f(q8[j]), qf1 = b2f(q8n[j]);
                a[j]  = f2b(qf + uu);
                c0[j] = f2b(qf + vv);
                c1[j] = f2b(qf1 + vv);
            }
            quf[ks]  = *(bhalf8*)a;
            qvf0[ks] = *(bhalf8*)c0;
            qvf1[ks] = *(bhalf8*)c1;
        }
    }

    floatx4 O[4];
    #pragma unroll
    for (int i = 0; i < 4; i++) O[i] = (floatx4){0.f,0.f,0.f,0.f};
    float m_r[4], l_r[4];
    #pragma unroll
    for (int r = 0; r < 4; r++){ m_r[r] = -INFINITY; l_r[r] = 0.f; }

    u16* pbw = Pb + w * 16 * 90;
    const int prow0 = (7 - w) * 16 + ln15;   // band row base (127-offset space)

    int s0 = z * (T_ / 2);
    for (int it = 0; it < 16; it++, s0 += 64){
        const int diff = s0 - t0;
        __syncthreads();   // barrier 1: previous tile fully consumed
        // ---- stage K, V, Pos via global_load_lds (pre-swizzled source) ----
        {
            gload16(kg + (size_t)(s0 + srowg) * 768 + swz8 * 8, &Ks[(w * 8) * 64]);
            gload16(vtg + (size_t)srowg * T_ + s0 + swz8 * 8,  &Vs[(w * 8) * 64]);
            int jb = (diff <= 64) ? (T_ - 128 + diff) : (diff - 129);
            #pragma unroll
            for (int j = 0; j < 3; j++){
                int jj = jb + j * 64 + srowg;
                const u16* ga = ((unsigned)jj < (unsigned)T_)
                                ? pg + (size_t)jj * D_ + swz8 * 8 : zbuf;
                gload16(ga, &Pos[(j * 64 + w * 8) * 64]);
            }
        }
        __syncthreads();   // barrier 2: tile ready (barrier drains vmcnt)

        // ---- band first (keeps Bacc/S from being co-live) ----
        floatx4 Bacc[5];
        #pragma unroll
        for (int i = 0; i < 5; i++) Bacc[i] = (floatx4){0.f,0.f,0.f,0.f};
        #pragma unroll
        for (int ks = 0; ks < 2; ks++){
            bhalf8 av = (diff <= 64) ? qvf0[ks] : qvf1[ks];
            #pragma unroll
            for (int n5 = 0; n5 < 5; n5++){
                bhalf8 bf = *(const bhalf8*)&Pos[(prow0 + n5 * 16) * 64
                                                 + (((ks << 2) + quad) ^ lsw) * 8];
                Bacc[n5] = __builtin_amdgcn_mfma_f32_16x16x32_bf16(av, bf, Bacc[n5], 0, 0, 0);
            }
        }
        if (diff == 0 || diff == 64){
            // mixed diagonal tile: s>t half via direct-global pos fragments
            int jb2 = diff - 129;
            #pragma unroll
            for (int ks = 0; ks < 2; ks++){
                #pragma unroll
                for (int n5 = 0; n5 < 5; n5++){
                    int jj = jb2 + prow0 + n5 * 16;
                    const u16* pp = ((unsigned)jj < (unsigned)T_)
                        ? pg + (size_t)jj * D_ + ks * 32 + quad * 8 : zbuf;
                    Bacc[n5] = __builtin_amdgcn_mfma_f32_16x16x32_bf16(qvf1[ks], *(const bhalf8*)pp,
                                                                       Bacc[n5], 0, 0, 0);
                }
            }
        }
        // ---- wave-local band strip write (Bacc dies here) ----
        #pragma unroll
        for (int n5 = 0; n5 < 5; n5++)
            #pragma unroll
            for (int r = 0; r < 4; r++)
                pbw[(quad * 4 + r) * 90 + n5 * 16 + ln15] = f2b(Bacc[n5][r]);

        // ---- QK ----
        floatx4 S[4];
        #pragma unroll
        for (int i = 0; i < 4; i++) S[i] = (floatx4){0.f,0.f,0.f,0.f};
        #pragma unroll
        for (int ks = 0; ks < 2; ks++){
            #pragma unroll
            for (int nt = 0; nt < 4; nt++){
                bhalf8 bf = *(const bhalf8*)&Ks[(nt * 16 + ln15) * 64
                                                + (((ks << 2) + quad) ^ lsw) * 8];
                S[nt] = __builtin_amdgcn_mfma_f32_16x16x32_bf16(quf[ks], bf, S[nt], 0, 0, 0);
            }
        }
        // ---- shifted band read + score ----
        float sc[4][4];
        #pragma unroll
        for (int nt = 0; nt < 4; nt++)
            #pragma unroll
            for (int r = 0; r < 4; r++){
                int i = quad * 4 + r;
                int c = nt * 16 + ln15 + 15 - i;
                sc[nt][r] = (S[nt][r] + b2f(pbw[i * 90 + c])) * 0.0625f;
            }
        // ---- online softmax (__expf), DPP reductions ----
        #pragma unroll
        for (int r = 0; r < 4; r++){
            float rowm = fmaxf(fmaxf(sc[0][r], sc[1][r]), fmaxf(sc[2][r], sc[3][r]));
            rowm = dpp16_max(rowm);
            float mnew = fmaxf(m_r[r], rowm);
            float alpha = __expf(m_r[r] - mnew);
            float rs = 0.f;
            #pragma unroll
            for (int nt = 0; nt < 4; nt++){ sc[nt][r] = __expf(sc[nt][r] - mnew); rs += sc[nt][r]; }
            rs = dpp16_add(rs);
            l_r[r] = l_r[r] * alpha + rs;
            m_r[r] = mnew;
            O[0][r] *= alpha; O[1][r] *= alpha; O[2][r] *= alpha; O[3][r] *= alpha;
        }
        #pragma unroll
        for (int nt = 0; nt < 4; nt++)
            #pragma unroll
            for (int r = 0; r < 4; r++)
                pbw[(quad * 4 + r) * 90 + nt * 16 + ln15] = f2b(sc[nt][r]);
        // ---- PV (strip is wave-private: no barrier needed) ----
        #pragma unroll
        for (int ks = 0; ks < 2; ks++){
            bhalf8 af = *(const bhalf8*)&pbw[ln15 * 90 + ks * 32 + quad * 8];
            #pragma unroll
            for (int nt = 0; nt < 4; nt++){
                bhalf8 bf = *(const bhalf8*)&Vs[(nt * 16 + ln15) * 64
                                                + (((ks << 2) + quad) ^ lsw) * 8];
                O[nt] = __builtin_amdgcn_mfma_f32_16x16x32_bf16(af, bf, O[nt], 0, 0, 0);
            }
        }
    }
    #pragma unroll
    for (int r = 0; r < 4; r++){
        int t = t0 + w * 16 + quad * 4 + r;
        size_t row = (size_t)(z * 32768 + bh * 2048 + t);
        #pragma unroll
        for (int nt = 0; nt < 4; nt++)
            Op[row * 64 + nt * 16 + ln15] = O[nt][r];
        if (ln15 == 0){
            ml[row * 2 + 0] = m_r[r];
            ml[row * 2 + 1] = l_r[r];
        }
    }
}

// ---------------- merge split-K attention partials ----------------
__global__ __launch_bounds__(256) void amerge_kernel(const float* __restrict__ Op,
        const float* __restrict__ ml, u16* __restrict__ ctx){
    int gid = blockIdx.x * 256 + threadIdx.x;
    int row = gid >> 4, d4 = (gid & 15) * 4;
    int bh = row >> 11, t = row & 2047;
    int b = bh >> 2, h = bh & 3;
    float m1 = ml[(size_t)row * 2], l1 = ml[(size_t)row * 2 + 1];
    float m2 = ml[(size_t)(32768 + row) * 2], l2 = ml[(size_t)(32768 + row) * 2 + 1];
    float m = fmaxf(m1, m2);
    float a1 = __expf(m1 - m), a2 = __expf(m2 - m);
    float invl = 1.f / (l1 * a1 + l2 * a2);
    float4 o1 = *(const float4*)(Op + (size_t)row * 64 + d4);
    float4 o2 = *(const float4*)(Op + (size_t)(32768 + row) * 64 + d4);
    ushort4 o;
    o.x = f2b((o1.x * a1 + o2.x * a2) * invl);
    o.y = f2b((o1.y * a1 + o2.y * a2) * invl);
    o.z = f2b((o1.z * a1 + o2.z * a2) * invl);
    o.w = f2b((o1.w * a1 + o2.w * a2) * invl);
    *(ushort4*)(ctx + ((size_t)(b * T_ + t)) * D_ + h * DH_ + d4) = o;
}

// ------- depthwise conv K=7, fused GLU tile-load, wave-reduced GN stats -------
// GLU (a * lrelu(g)) computed during tile build from ypw1's a/g halves.
// ydw intermediate bf16 (stats stay f32 in-register).
#define TT_ 32
__global__ __launch_bounds__(256) void dw2_kernel(const u16* __restrict__ ypw1,
        const float* __restrict__ w, const float* __restrict__ bias,
        u16* __restrict__ y, float* __restrict__ stats){
    __shared__ u16 tile[(TT_ + 6) * INNER_];
    int tid = threadIdx.x;
    int t0 = blockIdx.x * TT_, b = blockIdx.y;
    for (int uu = tid; uu < (TT_ + 6) * 64; uu += 256){
        int row = uu >> 6, c8 = (uu & 63) * 8;
        int t = t0 + row - 3;
        u16 o8[8] = {0,0,0,0,0,0,0,0};
        if ((unsigned)t < (unsigned)T_){
            u16 a8[8], g8[8];
            const u16* rp = ypw1 + ((size_t)(b * T_ + t)) * 1024;
            *(float4*)a8 = *(const float4*)(rp + c8);
            *(float4*)g8 = *(const float4*)(rp + 512 + c8);
            #pragma unroll
            for (int j = 0; j < 8; j++) o8[j] = f2b(b2f(a8[j]) * lrelu(b2f(g8[j])));
        }
        *(float4*)&tile[row * INNER_ + c8] = *(float4*)o8;
    }
    __syncthreads();
    int c8 = (tid & 63) * 8, trow = tid >> 6;
    float wreg[7][8], bv[8];
    #pragma unroll
    for (int j = 0; j < 8; j++){
        bv[j] = bias[c8 + j];
        #pragma unroll
        for (int kk = 0; kk < 7; kk++) wreg[kk][j] = w[(c8 + j) * 7 + kk];
    }
    float s1 = 0.f, s2 = 0.f;
    for (int tt = trow; tt < TT_; tt += 4){
        float acc[8];
        #pragma unroll
        for (int j = 0; j < 8; j++) acc[j] = bv[j];
        #pragma unroll
        for (int kk = 0; kk < 7; kk++){
            u16 r8[8];
            *(float4*)r8 = *(const float4*)&tile[(tt + kk) * INNER_ + c8];
            #pragma unroll
            for (int j = 0; j < 8; j++) acc[j] += b2f(r8[j]) * wreg[kk][j];
        }
        u16 o8[8];
        #pragma unroll
        for (int j = 0; j < 8; j++) o8[j] = f2b(acc[j]);
        *(float4*)(y + ((size_t)(b * T_ + t0 + tt)) * INNER_ + c8) = *(float4*)o8;
        #pragma unroll
        for (int j = 0; j < 8; j++){ s1 += acc[j]; s2 += acc[j] * acc[j]; }
    }
    #pragma unroll
    for (int mk = 1; mk < 64; mk <<= 1){
        s1 += __shfl_xor(s1, mk, 64);
        s2 += __shfl_xor(s2, mk, 64);
    }
    if ((tid & 63) == 0){
        atomicAdd(&stats[b * 2], s1);
        atomicAdd(&stats[b * 2 + 1], s2);
    }
}

// ---------------- GroupNorm(1) apply + leaky, bf16 in/out ----------------
__global__ __launch_bounds__(256) void gn_kernel(const u16* __restrict__ y,
        const float* __restrict__ g, const float* __restrict__ b2,
        const float* __restrict__ stats, u16* __restrict__ out){
    int idx8 = (blockIdx.x * 256 + threadIdx.x) * 8;
    int b = idx8 / (T_ * INNER_);
    int i = idx8 & (INNER_ - 1);
    const float invN = 1.f / (float)(T_ * INNER_);
    float mean = stats[b * 2] * invN;
    float var  = stats[b * 2 + 1] * invN - mean * mean;
    float rs = rsqrtf(var + 1e-5f);
    u16 v8[8], o8[8];
    *(float4*)v8 = *(const float4*)(y + idx8);
    #pragma unroll
    for (int j = 0; j < 8; j++)
        o8[j] = f2b(lrelu((b2f(v8[j]) - mean) * rs * g[i + j] + b2[i + j]));
    *(float4*)(out + idx8) = *(float4*)o8;
}

extern "C" void kernel_launch(void* const* d_in, const int* in_sizes, int n_in,
                              void* d_out, int out_size, void* d_ws, size_t ws_size,
                              hipStream_t stream){
    const float* x        = (const float*)d_in[0];
    const float* enc      = (const float*)d_in[1];
    const float* ff_ln_g  = (const float*)d_in[3];
    const float* ff_ln_b  = (const float*)d_in[4];
    const float* ff_w1    = (const float*)d_in[5];
    const float* ff_b1    = (const float*)d_in[6];
    const float* ff_w2    = (const float*)d_in[7];
    const float* ff_b2    = (const float*)d_in[8];
    const float* at_ln_g  = (const float*)d_in[9];
    const float* at_ln_b  = (const float*)d_in[10];
    const float* q_w      = (const float*)d_in[11];
    const float* q_b      = (const float*)d_in[12];
    const float* k_w      = (const float*)d_in[13];
    const float* v_w      = (const float*)d_in[14];
    const float* pos_w    = (const float*)d_in[15];
    const float* u_bias   = (const float*)d_in[16];
    const float* v_bias   = (const float*)d_in[17];
    const float* out_w    = (const float*)d_in[18];
    const float* out_b    = (const float*)d_in[19];
    const float* cm_ln_g  = (const float*)d_in[20];
    const float* cm_ln_b  = (const float*)d_in[21];
    const float* pw1_w    = (const float*)d_in[22];
    const float* pw1_b    = (const float*)d_in[23];
    const float* dw_w     = (const float*)d_in[24];
    const float* dw_b     = (const float*)d_in[25];
    const float* gn_g     = (const float*)d_in[26];
    const float* gn_b     = (const float*)d_in[27];
    const float* pw2_w    = (const float*)d_in[28];
    const float* pw2_b    = (const float*)d_in[29];
    float* out = (float*)d_out;

    char* ws = (char*)d_ws;
    u16*   y1bf = (u16*)(ws + 0);
    u16*   ypw1 = (u16*)(ws + 0);
    float* Op   = (float*)(ws + 0);
    float* ml   = (float*)(ws + ((size_t)16 << 20));
    u16*   ydw  = (u16*)(ws + ((size_t)16 << 20));
    u16*   qkv  = (u16*)(ws + ((size_t)32 << 20));
    u16*   vbT  = (u16*)(ws + ((size_t)44 << 20));
    u16*   ctxb = (u16*)(ws + ((size_t)48 << 20));
    u16*   posb = (u16*)(ws + ((size_t)52 << 20));
    u16*   lnbuf= (u16*)(ws + ((size_t)53 << 20));
    float* x1   = (float*)(ws + ((size_t)57 << 20));
    float* x2   = (float*)(ws + ((size_t)65 << 20));
    u16*   gnb  = (u16*)(ws + ((size_t)36 << 20));
    char* W = ws + ((size_t)81 << 20);
    u16* ff1w  = (u16*)(W);
    u16* ff2w  = (u16*)(W + ((size_t)2 << 20));
    u16* qkvw  = (u16*)(W + ((size_t)3 << 20));
    u16* kw    = qkvw + 65536;
    u16* vw    = qkvw + 131072;
    u16* posw  = (u16*)(W + ((size_t)3 << 20) + (384u << 10));
    u16* outw  = (u16*)(W + ((size_t)4 << 20));
    u16* pw1w  = (u16*)(W + ((size_t)5 << 20));
    u16* pw2w  = (u16*)(W + ((size_t)6 << 20));
    u16* encb  = (u16*)(W + ((size_t)7 << 20));
    u16* zbuf  = (u16*)(W + ((size_t)8 << 20));
    float* stats    = (float*)(W + ((size_t)8 << 20) + 4096);
    float* qkv_bias = (float*)(W + ((size_t)8 << 20) + 8192);

    const int MBT = B_ * T_;

    hipMemsetAsync(W + ((size_t)8 << 20), 0, 16384, stream);
    hipMemcpyAsync(qkv_bias, q_b, 256 * sizeof(float), hipMemcpyDeviceToDevice, stream);
    cast4_kernel<<<dim3(512, 4), 256, 0, stream>>>(
        ff_w2, ff2w, 256*1024, pw1_w, pw1w, 1024*256,
        pw2_w, pw2w, 256*512,  enc,   encb, 2048*256);
    castT5_kernel<<<dim3(16, 5), 256, 0, stream>>>(
        q_w, k_w, v_w, pos_w, out_w, qkvw, kw, vw, posw, outw);
    castFF1_kernel<<<3072, 256, 0, stream>>>(ff_w1, ff1w);

    // --- FeedForward ---
    ln_kernel<<<MBT/4, 256, 0, stream>>>(x, ff_ln_g, ff_ln_b, lnbuf);
    gemm_bf<64,128,1,true,true,false,true><<<dim3(FFI_/128, MBT/64), 256, 0, stream>>>(
        lnbuf, ff1w, ff_b1, nullptr, y1bf, MBT, FFI_, 3*D_, 0.f, zbuf);
    gemm_bf<64,64,0,true,false,true,false><<<dim3(D_/64, MBT/64), 256, 0, stream>>>(
        y1bf, ff2w, ff_b2, x, x1, MBT, D_, FFI_, 0.5f, nullptr);

    // --- Relative MHSA ---
    ln_kernel<<<MBT/4, 256, 0, stream>>>(x1, at_ln_g, at_ln_b, lnbuf);
    gemm_bf<128,64,0,true,false,false,true><<<dim3(768/64, MBT/128), 256, 0, stream>>>(
        lnbuf, qkvw, qkv_bias, nullptr, qkv, MBT, 768, D_, 0.f, nullptr);
    gemm_bf<128,64,0,false,false,false,true><<<dim3(D_/64, T_/128), 256, 0, stream>>>(
        encb, posw, nullptr, nullptr, posb, T_, D_, D_, 0.f, nullptr);
    vT_kernel<<<dim3(T_/64, D_/64, B_), 256, 0, stream>>>(qkv, vbT);
    attn11_kernel<<<dim3(T_/128, B_*H_, 2), 512, 0, stream>>>(
        qkv, vbT, posb, u_bias, v_bias, Op, ml, zbuf);
    amerge_kernel<<<(32768 * 16) / 256, 256, 0, stream>>>(Op, ml, ctxb);
    gemm_bf<64,64,0,true,false,true,false><<<dim3(D_/64, MBT/64), 256, 0, stream>>>(
        ctxb, outw, out_b, x1, x2, MBT, D_, D_, 1.f, nullptr);

    // --- Conformer conv module ---
    ln_kernel<<<MBT/4, 256, 0, stream>>>(x2, cm_ln_g, cm_ln_b, lnbuf);
    gemm_bf<64,128,0,true,false,false,true><<<dim3(FFI_/128, MBT/64), 256, 0, stream>>>(
        lnbuf, pw1w, pw1_b, nullptr, ypw1, MBT, FFI_, D_, 0.f, nullptr);
    dw2_kernel<<<dim3(T_/TT_, B_), 256, 0, stream>>>(ypw1, dw_w, dw_b, ydw, stats);
    gn_kernel<<<(MBT * INNER_) / (256 * 8), 256, 0, stream>>>(ydw, gn_g, gn_b, stats, gnb);
    gemm_bf<64,64,0,true,false,true,false><<<dim3(D_/64, MBT/64), 256, 0, stream>>>(
        gnb, pw2w, pw2_b, x2, out, MBT, D_, INNER_, 1.f, nullptr);
}

// Round 19
// 341.483 us; speedup vs baseline: 1.0044x; 1.0044x over previous
//
#include <hip/hip_runtime.h>
#include <math.h>

#define B_ 4
#define T_ 2048
#define D_ 256
#define H_ 4
#define DH_ 64
#define INNER_ 512
#define FFI_ 1024

typedef unsigned short u16;
typedef __bf16 bhalf;
typedef bhalf bhalf8 __attribute__((ext_vector_type(8)));
typedef float floatx4 __attribute__((ext_vector_type(4)));

__device__ __forceinline__ float lrelu(float x){ return x >= 0.f ? x : 0.3f * x; }

// native RTNE bf16 convert (v_cvt_pk_bf16_f32)
__device__ __forceinline__ u16 f2b(float f){
    __bf16 h = (__bf16)f;
    return __builtin_bit_cast(unsigned short, h);
}
__device__ __forceinline__ float b2f(u16 v){ return __uint_as_float((unsigned)v << 16); }

__device__ __forceinline__ void gload16(const void* g, void* l){
    __builtin_amdgcn_global_load_lds(
        (const __attribute__((address_space(1))) unsigned*)g,
        (__attribute__((address_space(3))) unsigned*)l, 16, 0, 0);
}

// ---- DPP 16-lane rotate-reduce (row_ror:1/2/4/8), pure VALU, no LDS pipe ----
__device__ __forceinline__ float dpp16_add(float x){
    int t;
    t = __builtin_amdgcn_update_dpp(0, __float_as_int(x), 0x121, 0xf, 0xf, false); x += __int_as_float(t);
    t = __builtin_amdgcn_update_dpp(0, __float_as_int(x), 0x122, 0xf, 0xf, false); x += __int_as_float(t);
    t = __builtin_amdgcn_update_dpp(0, __float_as_int(x), 0x124, 0xf, 0xf, false); x += __int_as_float(t);
    t = __builtin_amdgcn_update_dpp(0, __float_as_int(x), 0x128, 0xf, 0xf, false); x += __int_as_float(t);
    return x;
}
__device__ __forceinline__ float dpp16_max(float x){
    int t;
    t = __builtin_amdgcn_update_dpp(0, __float_as_int(x), 0x121, 0xf, 0xf, false); x = fmaxf(x, __int_as_float(t));
    t = __builtin_amdgcn_update_dpp(0, __float_as_int(x), 0x122, 0xf, 0xf, false); x = fmaxf(x, __int_as_float(t));
    t = __builtin_amdgcn_update_dpp(0, __float_as_int(x), 0x124, 0xf, 0xf, false); x = fmaxf(x, __int_as_float(t));
    t = __builtin_amdgcn_update_dpp(0, __float_as_int(x), 0x128, 0xf, 0xf, false); x = fmaxf(x, __int_as_float(t));
    return x;
}

// ------------- weight/activation cast kernels (float4-vectorized) -------------
__global__ __launch_bounds__(256) void cast4_kernel(
        const float* __restrict__ s0, u16* d0, int n0_,
        const float* __restrict__ s1, u16* d1, int n1_,
        const float* __restrict__ s2, u16* d2, int n2_,
        const float* __restrict__ s3, u16* d3, int n3_){
    int idx4 = (blockIdx.x * 256 + threadIdx.x) * 4;
    int y = blockIdx.y;
    const float* s = y==0 ? s0 : y==1 ? s1 : y==2 ? s2 : s3;
    u16* d        = y==0 ? d0 : y==1 ? d1 : y==2 ? d2 : d3;
    int n         = y==0 ? n0_ : y==1 ? n1_ : y==2 ? n2_ : n3_;
    if (idx4 < n){                       // n % 4 == 0 for all inputs
        float4 v = *(const float4*)(s + idx4);
        ushort4 o;
        o.x = f2b(v.x); o.y = f2b(v.y); o.z = f2b(v.z); o.w = f2b(v.w);
        *(ushort4*)(d + idx4) = o;
    }
}

// 256x256 transpose-cast via LDS tile (vT_kernel-proven pattern):
// d[n][k] = bf16(s[k][n]); coalesced float4 reads + float4 writes.
__global__ __launch_bounds__(256) void castT5_kernel(
        const float* __restrict__ s0, const float* __restrict__ s1,
        const float* __restrict__ s2, const float* __restrict__ s3,
        const float* __restrict__ s4,
        u16* d0, u16* d1, u16* d2, u16* d3, u16* d4){
    __shared__ u16 tile[64 * 68];
    int y = blockIdx.y;
    const float* s = y==0 ? s0 : y==1 ? s1 : y==2 ? s2 : y==3 ? s3 : s4;
    u16* d        = y==0 ? d0 : y==1 ? d1 : y==2 ? d2 : y==3 ? d3 : d4;
    int k0 = (blockIdx.x & 3) * 64, n0 = (blockIdx.x >> 2) * 64;
    int tid = threadIdx.x;
    // load: tile[k][n] <- bf16(s[k0+k][n0+n]), 4 f32 per thread pass
    for (int u = tid; u < 1024; u += 256){
        int r = u >> 4, c4 = (u & 15) * 4;
        float4 v = *(const float4*)(s + (size_t)(k0 + r) * 256 + n0 + c4);
        u16 o4[4];
        o4[0] = f2b(v.x); o4[1] = f2b(v.y); o4[2] = f2b(v.z); o4[3] = f2b(v.w);
        *(uint2*)&tile[r * 68 + c4] = *(uint2*)o4;
    }
    __syncthreads();
    // write: d[n0+n][k0+k] <- tile[k][n], 8 u16 per thread pass
    for (int u = tid; u < 512; u += 256){
        int n = u >> 3, k8 = (u & 7) * 8;
        u16 g[8];
        #pragma unroll
        for (int j = 0; j < 8; j++) g[j] = tile[(k8 + j) * 68 + n];
        *(float4*)(d + (size_t)(n0 + n) * 256 + k0 + k8) = *(float4*)g;
    }
}

__global__ __launch_bounds__(256) void castFF1_kernel(const float* __restrict__ s, u16* d){
    int idx = blockIdx.x * 256 + threadIdx.x;
    int n = idx / 768, rem = idx - n * 768;
    int kc = rem >> 8, c = rem & 255;
    d[idx] = f2b(s[(n * 256 + c) * 3 + kc]);
}

// ---------------- LayerNorm: one wave per 256-elem row ----------------
__global__ __launch_bounds__(256) void ln_kernel(const float* __restrict__ x,
        const float* __restrict__ g, const float* __restrict__ b,
        u16* __restrict__ out){
    int wave = threadIdx.x >> 6, lane = threadIdx.x & 63;
    int row = blockIdx.x * 4 + wave;
    size_t base = (size_t)row * D_ + lane * 4;
    float4 v = *(const float4*)(x + base);
    float s = v.x + v.y + v.z + v.w;
    #pragma unroll
    for (int mk = 1; mk < 64; mk <<= 1) s += __shfl_xor(s, mk, 64);
    float mean = s * (1.f / D_);
    float4 d = make_float4(v.x - mean, v.y - mean, v.z - mean, v.w - mean);
    float q = d.x*d.x + d.y*d.y + d.z*d.z + d.w*d.w;
    #pragma unroll
    for (int mk = 1; mk < 64; mk <<= 1) q += __shfl_xor(q, mk, 64);
    float rs = rsqrtf(q * (1.f / D_) + 1e-5f);
    float4 gg = *(const float4*)(g + lane * 4);
    float4 bb = *(const float4*)(b + lane * 4);
    ushort4 o;
    o.x = f2b(d.x * rs * gg.x + bb.x);
    o.y = f2b(d.y * rs * gg.y + bb.y);
    o.z = f2b(d.z * rs * gg.z + bb.z);
    o.w = f2b(d.w * rs * gg.w + bb.w);
    *(ushort4*)(out + base) = o;
}

// ===== bf16 MFMA GEMM, BK=64, XOR-swizzled LDS (conflict-free b128 reads) =====
// Wave tilings: 128x128 (4 waves, 64x64 each), 128x64 (4 waves, 32x64),
// 64x64 (4 waves, 32x32), 64x128 (4 waves, 32x64 each).
template<int BM, int BN, int AMODE, bool BIAS, bool ACT, bool RES, bool OUTBF>
__global__ __launch_bounds__(256) void gemm_bf(
        const u16* __restrict__ A, const u16* __restrict__ Bw,
        const float* __restrict__ bias, const float* __restrict__ res,
        void* __restrict__ C, int M, int N, int K, float alpha,
        const u16* __restrict__ zbuf){
    __shared__ __align__(16) u16 As[BM * 64];
    __shared__ __align__(16) u16 Bs[BN * 64];
    const int tid = threadIdx.x;
    const int lane = tid & 63, w = tid >> 6;
    const int ln15 = lane & 15, quad = lane >> 4;
    const int lsw = ln15 & 7;
    const int m0 = blockIdx.y * BM, n0 = blockIdx.x * BN;
    const int srow8 = lane >> 3;                 // row within 8-row stage chunk
    const int swzc  = ((lane & 7) ^ srow8) * 8;  // pre-swizzled source col (u16)
    const bool M64N128 = (BM == 64 && BN == 128);
    const int MT = (BM == 64) ? 2 : ((BN == 128) ? 4 : 2);
    const int NT = M64N128 ? 4 : ((BM == 64) ? 2 : 4);
    const int wm = M64N128 ? (w & 1) : ((BM == 64 || BN == 128) ? (w >> 1) : w);
    const int wn = M64N128 ? (w >> 1) : ((BM == 64 || BN == 128) ? (w & 1) : 0);
    const int mbase = M64N128 ? wm * 32
                     : ((BM == 64) ? wm * 32 : ((BN == 128) ? wm * 64 : w * 32));
    const int nbase = M64N128 ? wn * 64
                     : ((BM == 64) ? wn * 32 : ((BN == 128) ? wn * 64 : 0));
    const int JA = BM / 32;                      // A stage gloads per wave
    const int JB = BN / 32;

    floatx4 acc[4][4];
    #pragma unroll
    for (int i = 0; i < 4; i++)
        #pragma unroll
        for (int j = 0; j < 4; j++)
            acc[i][j] = (floatx4){0.f, 0.f, 0.f, 0.f};

    for (int k0 = 0; k0 < K; k0 += 64){
        __syncthreads();
        #pragma unroll
        for (int j = 0; j < JA; j++){
            int mrow = m0 + w * (BM / 4) + j * 8 + srow8;
            const u16* ga;
            if (AMODE == 0){
                ga = A + (size_t)mrow * K + k0 + swzc;
            } else {
                int bb = mrow >> 11, t = mrow & (T_ - 1);
                int kc = k0 >> 8;
                int c = (k0 & 255) + swzc;        // swzc<64, k0%64==0 -> no 256-cross
                int t2 = t + kc - 1;
                ga = ((unsigned)t2 < (unsigned)T_)
                     ? A + ((size_t)(bb * T_ + t2)) * D_ + c : zbuf;
            }
            gload16(ga, &As[(w * (BM / 4) + j * 8) * 64]);
        }
        #pragma unroll
        for (int j = 0; j < JB; j++){
            const u16* gb = Bw + (size_t)(n0 + w * (BN / 4) + j * 8 + srow8) * K + k0 + swzc;
            gload16(gb, &Bs[(w * (BN / 4) + j * 8) * 64]);
        }
        __syncthreads();
        #pragma unroll
        for (int ks = 0; ks < 2; ks++){
            const int rc = (((ks << 2) + quad) ^ lsw) * 8;
            bhalf8 af[4], bfr[4];
            #pragma unroll
            for (int mi = 0; mi < MT; mi++)
                af[mi] = *(const bhalf8*)&As[(mbase + mi * 16 + ln15) * 64 + rc];
            #pragma unroll
            for (int ni = 0; ni < NT; ni++)
                bfr[ni] = *(const bhalf8*)&Bs[(nbase + ni * 16 + ln15) * 64 + rc];
            #pragma unroll
            for (int mi = 0; mi < MT; mi++)
                #pragma unroll
                for (int ni = 0; ni < NT; ni++)
                    acc[mi][ni] = __builtin_amdgcn_mfma_f32_16x16x32_bf16(
                        af[mi], bfr[ni], acc[mi][ni], 0, 0, 0);
        }
    }
    #pragma unroll
    for (int mi = 0; mi < MT; mi++){
        #pragma unroll
        for (int ni = 0; ni < NT; ni++){
            int n = n0 + nbase + ni * 16 + ln15;
            float bv = BIAS ? bias[n] : 0.f;
            #pragma unroll
            for (int r = 0; r < 4; r++){
                int m = m0 + mbase + mi * 16 + quad * 4 + r;
                float val = acc[mi][ni][r] + bv;
                if (ACT) val = lrelu(val);
                if (RES) val = res[(size_t)m * N + n] + alpha * val;
                if (OUTBF) ((u16*)C)[(size_t)m * N + n] = f2b(val);
                else       ((float*)C)[(size_t)m * N + n] = val;
            }
        }
    }
}

// ---------------- V transpose: qkv[:,512+..] [B*T][768] -> vbT [B][256][T] ----------------
__global__ __launch_bounds__(256) void vT_kernel(const u16* __restrict__ qkv, u16* __restrict__ vbT){
    __shared__ u16 tile[64 * 68];
    int t0 = blockIdx.x * 64, d0 = blockIdx.y * 64, b = blockIdx.z;
    int tid = threadIdx.x;
    for (int u = tid; u < 512; u += 256){
        int r = u >> 3, c8 = (u & 7) * 8;
        *(float4*)&tile[r * 68 + c8] =
            *(const float4*)(qkv + ((size_t)(b * T_ + t0 + r)) * 768 + 512 + d0 + c8);
    }
    __syncthreads();
    for (int u = tid; u < 512; u += 256){
        int d = u >> 3, t8 = (u & 7) * 8;
        u16 g[8];
        #pragma unroll
        for (int j = 0; j < 8; j++) g[j] = tile[(t8 + j) * 68 + d];
        *(float4*)(vbT + ((size_t)(b * 256 + d0 + d)) * T_ + t0 + t8) = *(float4*)g;
    }
}

// ========== 8-wave QBLK=128 flash attention, gload_lds staging + XOR swizzle ==========
// (round-4..18 HW-verified structure; this round: Op partials stored as bf16
// to halve the attn->amerge round-trip, merge math stays f32)
__global__ __launch_bounds__(512) void attn11_kernel(
        const u16* __restrict__ qkv, const u16* __restrict__ vbT,
        const u16* __restrict__ posb,
        const float* __restrict__ ub, const float* __restrict__ vbias,
        u16* __restrict__ Op, float* __restrict__ ml,
        const u16* __restrict__ zbuf)
{
    __shared__ __align__(16) u16 Ks[64 * 64];
    __shared__ __align__(16) u16 Vs[64 * 64];
    __shared__ __align__(16) u16 Pos[192 * 64];
    __shared__ __align__(16) u16 Pb[8 * 16 * 90];

    const int tid = threadIdx.x;
    const int lane = tid & 63, w = tid >> 6;
    const int ln15 = lane & 15, quad = lane >> 4;
    const int lsw = ln15 & 7;                 // read-side XOR key (row&7 == ln15&7)

    // XCD-locality swizzle: 512 = 8 xcd * 2 bh * 2 z * 16 t-blocks (bijective)
    int wgid = blockIdx.x + 16 * (blockIdx.y + 16 * blockIdx.z);
    int xcd = wgid & 7, idx = wgid >> 3;               // idx in [0,64)
    const int bh = xcd * 2 + (idx >> 5);
    const int z  = (idx >> 4) & 1;
    const int t0 = (idx & 15) * 128;
    const int b = bh >> 2, h = bh & 3;

    const u16* qg  = qkv + (size_t)b * T_ * 768 + h * DH_;
    const u16* kg  = qkv + (size_t)b * T_ * 768 + 256 + h * DH_;
    const u16* vtg = vbT + ((size_t)(b * 256 + h * DH_)) * T_;
    const u16* pg  = posb + h * DH_;

    // staging geometry: wave w stages rows [w*8, w*8+8); lane -> (row, chunk)
    const int srow8 = lane >> 3;              // row within the wave's 8-row strip
    const int swz8  = (lane & 7) ^ srow8;     // pre-swizzled source chunk * 8 u16
    const int srowg = w * 8 + srow8;          // row within 64-row tile

    // ---- register Q fragments (wave w owns q-rows t0+w*16 .. +15) ----
    bhalf8 quf[2], qvf0[2], qvf1[2];
    {
        int qrow = t0 + w * 16 + ln15;
        #pragma unroll
        for (int ks = 0; ks < 2; ks++){
            int dof = ks * 32 + quad * 8;
            u16 q8[8];
            *(float4*)q8 = *(const float4*)(qg + (size_t)qrow * 768 + dof);
            u16 q8n[8] = {0,0,0,0,0,0,0,0};
            if (qrow + 1 < T_)
                *(float4*)q8n = *(const float4*)(qg + (size_t)(qrow + 1) * 768 + dof);
            u16 a[8], c0[8], c1[8];
            #pragma unroll
            for (int j = 0; j < 8; j++){
                float uu = ub[h * DH_ + dof + j];
                float vv = vbias[h * DH_ + dof + j];
                float qf = b2f(q8[j]), qf1 = b2f(q8n[j]);
                a[j]  = f2b(qf + uu);
                c0[j] = f2b(qf + vv);
                c1[j] = f2b(qf1 + vv);
            }
            quf[ks]  = *(bhalf8*)a;
            qvf0[ks] = *(bhalf8*)c0;
            qvf1[ks] = *(bhalf8*)c1;
        }
    }

    floatx4 O[4];
    #pragma unroll
    for (int i = 0; i < 4; i++) O[i] = (floatx4){0.f,0.f,0.f,0.f};
    float m_r[4], l_r[4];
    #pragma unroll
    for (int r = 0; r < 4; r++){ m_r[r] = -INFINITY; l_r[r] = 0.f; }

    u16* pbw = Pb + w * 16 * 90;
    const int prow0 = (7 - w) * 16 + ln15;   // band row base (127-offset space)

    int s0 = z * (T_ / 2);
    for (int it = 0; it < 16; it++, s0 += 64){
        const int diff = s0 - t0;
        __syncthreads();   // barrier 1: previous tile fully consumed
        // ---- stage K, V, Pos via global_load_lds (pre-swizzled source) ----
        {
            gload16(kg + (size_t)(s0 + srowg) * 768 + swz8 * 8, &Ks[(w * 8) * 64]);
            gload16(vtg + (size_t)srowg * T_ + s0 + swz8 * 8,  &Vs[(w * 8) * 64]);
            int jb = (diff <= 64) ? (T_ - 128 + diff) : (diff - 129);
            #pragma unroll
            for (int j = 0; j < 3; j++){
                int jj = jb + j * 64 + srowg;
                const u16* ga = ((unsigned)jj < (unsigned)T_)
                                ? pg + (size_t)jj * D_ + swz8 * 8 : zbuf;
                gload16(ga, &Pos[(j * 64 + w * 8) * 64]);
            }
        }
        __syncthreads();   // barrier 2: tile ready (barrier drains vmcnt)

        // ---- band first (keeps Bacc/S from being co-live) ----
        floatx4 Bacc[5];
        #pragma unroll
        for (int i = 0; i < 5; i++) Bacc[i] = (floatx4){0.f,0.f,0.f,0.f};
        #pragma unroll
        for (int ks = 0; ks < 2; ks++){
            bhalf8 av = (diff <= 64) ? qvf0[ks] : qvf1[ks];
            #pragma unroll
            for (int n5 = 0; n5 < 5; n5++){
                bhalf8 bf = *(const bhalf8*)&Pos[(prow0 + n5 * 16) * 64
                                                 + (((ks << 2) + quad) ^ lsw) * 8];
                Bacc[n5] = __builtin_amdgcn_mfma_f32_16x16x32_bf16(av, bf, Bacc[n5], 0, 0, 0);
            }
        }
        if (diff == 0 || diff == 64){
            // mixed diagonal tile: s>t half via direct-global pos fragments
            int jb2 = diff - 129;
            #pragma unroll
            for (int ks = 0; ks < 2; ks++){
                #pragma unroll
                for (int n5 = 0; n5 < 5; n5++){
                    int jj = jb2 + prow0 + n5 * 16;
                    const u16* pp = ((unsigned)jj < (unsigned)T_)
                        ? pg + (size_t)jj * D_ + ks * 32 + quad * 8 : zbuf;
                    Bacc[n5] = __builtin_amdgcn_mfma_f32_16x16x32_bf16(qvf1[ks], *(const bhalf8*)pp,
                                                                       Bacc[n5], 0, 0, 0);
                }
            }
        }
        // ---- wave-local band strip write (Bacc dies here) ----
        #pragma unroll
        for (int n5 = 0; n5 < 5; n5++)
            #pragma unroll
            for (int r = 0; r < 4; r++)
                pbw[(quad * 4 + r) * 90 + n5 * 16 + ln15] = f2b(Bacc[n5][r]);

        // ---- QK ----
        floatx4 S[4];
        #pragma unroll
        for (int i = 0; i < 4; i++) S[i] = (floatx4){0.f,0.f,0.f,0.f};
        #pragma unroll
        for (int ks = 0; ks < 2; ks++){
            #pragma unroll
            for (int nt = 0; nt < 4; nt++){
                bhalf8 bf = *(const bhalf8*)&Ks[(nt * 16 + ln15) * 64
                                                + (((ks << 2) + quad) ^ lsw) * 8];
                S[nt] = __builtin_amdgcn_mfma_f32_16x16x32_bf16(quf[ks], bf, S[nt], 0, 0, 0);
            }
        }
        // ---- shifted band read + score ----
        float sc[4][4];
        #pragma unroll
        for (int nt = 0; nt < 4; nt++)
            #pragma unroll
            for (int r = 0; r < 4; r++){
                int i = quad * 4 + r;
                int c = nt * 16 + ln15 + 15 - i;
                sc[nt][r] = (S[nt][r] + b2f(pbw[i * 90 + c])) * 0.0625f;
            }
        // ---- online softmax (__expf), DPP reductions ----
        #pragma unroll
        for (int r = 0; r < 4; r++){
            float rowm = fmaxf(fmaxf(sc[0][r], sc[1][r]), fmaxf(sc[2][r], sc[3][r]));
            rowm = dpp16_max(rowm);
            float mnew = fmaxf(m_r[r], rowm);
            float alpha = __expf(m_r[r] - mnew);
            float rs = 0.f;
            #pragma unroll
            for (int nt = 0; nt < 4; nt++){ sc[nt][r] = __expf(sc[nt][r] - mnew); rs += sc[nt][r]; }
            rs = dpp16_add(rs);
            l_r[r] = l_r[r] * alpha + rs;
            m_r[r] = mnew;
            O[0][r] *= alpha; O[1][r] *= alpha; O[2][r] *= alpha; O[3][r] *= alpha;
        }
        #pragma unroll
        for (int nt = 0; nt < 4; nt++)
            #pragma unroll
            for (int r = 0; r < 4; r++)
                pbw[(quad * 4 + r) * 90 + nt * 16 + ln15] = f2b(sc[nt][r]);
        // ---- PV (strip is wave-private: no barrier needed) ----
        #pragma unroll
        for (int ks = 0; ks < 2; ks++){
            bhalf8 af = *(const bhalf8*)&pbw[ln15 * 90 + ks * 32 + quad * 8];
            #pragma unroll
            for (int nt = 0; nt < 4; nt++){
                bhalf8 bf = *(const bhalf8*)&Vs[(nt * 16 + ln15) * 64
                                                + (((ks << 2) + quad) ^ lsw) * 8];
                O[nt] = __builtin_amdgcn_mfma_f32_16x16x32_bf16(af, bf, O[nt], 0, 0, 0);
            }
        }
    }
    #pragma unroll
    for (int r = 0; r < 4; r++){
        int t = t0 + w * 16 + quad * 4 + r;
        size_t row = (size_t)(z * 32768 + bh * 2048 + t);
        #pragma unroll
        for (int nt = 0; nt < 4; nt++)
            Op[row * 64 + nt * 16 + ln15] = f2b(O[nt][r]);
        if (ln15 == 0){
            ml[row * 2 + 0] = m_r[r];
            ml[row * 2 + 1] = l_r[r];
        }
    }
}

// ------------- merge split-K attention partials (bf16 partials, f32 math) -------------
__global__ __launch_bounds__(256) void amerge_kernel(const u16* __restrict__ Op,
        const float* __restrict__ ml, u16* __restrict__ ctx){
    int gid = blockIdx.x * 256 + threadIdx.x;
    int row = gid >> 4, d4 = (gid & 15) * 4;
    int bh = row >> 11, t = row & 2047;
    int b = bh >> 2, h = bh & 3;
    float m1 = ml[(size_t)row * 2], l1 = ml[(size_t)row * 2 + 1];
    float m2 = ml[(size_t)(32768 + row) * 2], l2 = ml[(size_t)(32768 + row) * 2 + 1];
    float m = fmaxf(m1, m2);
    float a1 = __expf(m1 - m), a2 = __expf(m2 - m);
    float invl = 1.f / (l1 * a1 + l2 * a2);
    u16 p1[4], p2[4];
    *(ushort4*)p1 = *(const ushort4*)(Op + (size_t)row * 64 + d4);
    *(ushort4*)p2 = *(const ushort4*)(Op + (size_t)(32768 + row) * 64 + d4);
    ushort4 o;
    o.x = f2b((b2f(p1[0]) * a1 + b2f(p2[0]) * a2) * invl);
    o.y = f2b((b2f(p1[1]) * a1 + b2f(p2[1]) * a2) * invl);
    o.z = f2b((b2f(p1[2]) * a1 + b2f(p2[2]) * a2) * invl);
    o.w = f2b((b2f(p1[3]) * a1 + b2f(p2[3]) * a2) * invl);
    *(ushort4*)(ctx + ((size_t)(b * T_ + t)) * D_ + h * DH_ + d4) = o;
}

// ------- depthwise conv K=7, fused GLU tile-load, wave-reduced GN stats -------
// GLU (a * lrelu(g)) computed during tile build from ypw1's a/g halves.
// ydw intermediate bf16 (stats stay f32 in-register).
#define TT_ 32
__global__ __launch_bounds__(256) void dw2_kernel(const u16* __restrict__ ypw1,
        const float* __restrict__ w, const float* __restrict__ bias,
        u16* __restrict__ y, float* __restrict__ stats){
    __shared__ u16 tile[(TT_ + 6) * INNER_];
    int tid = threadIdx.x;
    int t0 = blockIdx.x * TT_, b = blockIdx.y;
    for (int uu = tid; uu < (TT_ + 6) * 64; uu += 256){
        int row = uu >> 6, c8 = (uu & 63) * 8;
        int t = t0 + row - 3;
        u16 o8[8] = {0,0,0,0,0,0,0,0};
        if ((unsigned)t < (unsigned)T_){
            u16 a8[8], g8[8];
            const u16* rp = ypw1 + ((size_t)(b * T_ + t)) * 1024;
            *(float4*)a8 = *(const float4*)(rp + c8);
            *(float4*)g8 = *(const float4*)(rp + 512 + c8);
            #pragma unroll
            for (int j = 0; j < 8; j++) o8[j] = f2b(b2f(a8[j]) * lrelu(b2f(g8[j])));
        }
        *(float4*)&tile[row * INNER_ + c8] = *(float4*)o8;
    }
    __syncthreads();
    int c8 = (tid & 63) * 8, trow = tid >> 6;
    float wreg[7][8], bv[8];
    #pragma unroll
    for (int j = 0; j < 8; j++){
        bv[j] = bias[c8 + j];
        #pragma unroll
        for (int kk = 0; kk < 7; kk++) wreg[kk][j] = w[(c8 + j) * 7 + kk];
    }
    float s1 = 0.f, s2 = 0.f;
    for (int tt = trow; tt < TT_; tt += 4){
        float acc[8];
        #pragma unroll
        for (int j = 0; j < 8; j++) acc[j] = bv[j];
        #pragma unroll
        for (int kk = 0; kk < 7; kk++){
            u16 r8[8];
            *(float4*)r8 = *(const float4*)&tile[(tt + kk) * INNER_ + c8];
            #pragma unroll
            for (int j = 0; j < 8; j++) acc[j] += b2f(r8[j]) * wreg[kk][j];
        }
        u16 o8[8];
        #pragma unroll
        for (int j = 0; j < 8; j++) o8[j] = f2b(acc[j]);
        *(float4*)(y + ((size_t)(b * T_ + t0 + tt)) * INNER_ + c8) = *(float4*)o8;
        #pragma unroll
        for (int j = 0; j < 8; j++){ s1 += acc[j]; s2 += acc[j] * acc[j]; }
    }
    #pragma unroll
    for (int mk = 1; mk < 64; mk <<= 1){
        s1 += __shfl_xor(s1, mk, 64);
        s2 += __shfl_xor(s2, mk, 64);
    }
    if ((tid & 63) == 0){
        atomicAdd(&stats[b * 2], s1);
        atomicAdd(&stats[b * 2 + 1], s2);
    }
}

// ---------------- GroupNorm(1) apply + leaky, bf16 in/out ----------------
__global__ __launch_bounds__(256) void gn_kernel(const u16* __restrict__ y,
        const float* __restrict__ g, const float* __restrict__ b2,
        const float* __restrict__ stats, u16* __restrict__ out){
    int idx8 = (blockIdx.x * 256 + threadIdx.x) * 8;
    int b = idx8 / (T_ * INNER_);
    int i = idx8 & (INNER_ - 1);
    const float invN = 1.f / (float)(T_ * INNER_);
    float mean = stats[b * 2] * invN;
    float var  = stats[b * 2 + 1] * invN - mean * mean;
    float rs = rsqrtf(var + 1e-5f);
    u16 v8[8], o8[8];
    *(float4*)v8 = *(const float4*)(y + idx8);
    #pragma unroll
    for (int j = 0; j < 8; j++)
        o8[j] = f2b(lrelu((b2f(v8[j]) - mean) * rs * g[i + j] + b2[i + j]));
    *(float4*)(out + idx8) = *(float4*)o8;
}

extern "C" void kernel_launch(void* const* d_in, const int* in_sizes, int n_in,
                              void* d_out, int out_size, void* d_ws, size_t ws_size,
                              hipStream_t stream){
    const float* x        = (const float*)d_in[0];
    const float* enc      = (const float*)d_in[1];
    const float* ff_ln_g  = (const float*)d_in[3];
    const float* ff_ln_b  = (const float*)d_in[4];
    const float* ff_w1    = (const float*)d_in[5];
    const float* ff_b1    = (const float*)d_in[6];
    const float* ff_w2    = (const float*)d_in[7];
    const float* ff_b2    = (const float*)d_in[8];
    const float* at_ln_g  = (const float*)d_in[9];
    const float* at_ln_b  = (const float*)d_in[10];
    const float* q_w      = (const float*)d_in[11];
    const float* q_b      = (const float*)d_in[12];
    const float* k_w      = (const float*)d_in[13];
    const float* v_w      = (const float*)d_in[14];
    const float* pos_w    = (const float*)d_in[15];
    const float* u_bias   = (const float*)d_in[16];
    const float* v_bias   = (const float*)d_in[17];
    const float* out_w    = (const float*)d_in[18];
    const float* out_b    = (const float*)d_in[19];
    const float* cm_ln_g  = (const float*)d_in[20];
    const float* cm_ln_b  = (const float*)d_in[21];
    const float* pw1_w    = (const float*)d_in[22];
    const float* pw1_b    = (const float*)d_in[23];
    const float* dw_w     = (const float*)d_in[24];
    const float* dw_b     = (const float*)d_in[25];
    const float* gn_g     = (const float*)d_in[26];
    const float* gn_b     = (const float*)d_in[27];
    const float* pw2_w    = (const float*)d_in[28];
    const float* pw2_b    = (const float*)d_in[29];
    float* out = (float*)d_out;

    char* ws = (char*)d_ws;
    u16*   y1bf = (u16*)(ws + 0);
    u16*   ypw1 = (u16*)(ws + 0);
    u16*   Op   = (u16*)(ws + 0);
    float* ml   = (float*)(ws + ((size_t)16 << 20));
    u16*   ydw  = (u16*)(ws + ((size_t)16 << 20));
    u16*   qkv  = (u16*)(ws + ((size_t)32 << 20));
    u16*   vbT  = (u16*)(ws + ((size_t)44 << 20));
    u16*   ctxb = (u16*)(ws + ((size_t)48 << 20));
    u16*   posb = (u16*)(ws + ((size_t)52 << 20));
    u16*   lnbuf= (u16*)(ws + ((size_t)53 << 20));
    float* x1   = (float*)(ws + ((size_t)57 << 20));
    float* x2   = (float*)(ws + ((size_t)65 << 20));
    u16*   gnb  = (u16*)(ws + ((size_t)36 << 20));
    char* W = ws + ((size_t)81 << 20);
    u16* ff1w  = (u16*)(W);
    u16* ff2w  = (u16*)(W + ((size_t)2 << 20));
    u16* qkvw  = (u16*)(W + ((size_t)3 << 20));
    u16* kw    = qkvw + 65536;
    u16* vw    = qkvw + 131072;
    u16* posw  = (u16*)(W + ((size_t)3 << 20) + (384u << 10));
    u16* outw  = (u16*)(W + ((size_t)4 << 20));
    u16* pw1w  = (u16*)(W + ((size_t)5 << 20));
    u16* pw2w  = (u16*)(W + ((size_t)6 << 20));
    u16* encb  = (u16*)(W + ((size_t)7 << 20));
    u16* zbuf  = (u16*)(W + ((size_t)8 << 20));
    float* stats    = (float*)(W + ((size_t)8 << 20) + 4096);
    float* qkv_bias = (float*)(W + ((size_t)8 << 20) + 8192);

    const int MBT = B_ * T_;

    hipMemsetAsync(W + ((size_t)8 << 20), 0, 16384, stream);
    hipMemcpyAsync(qkv_bias, q_b, 256 * sizeof(float), hipMemcpyDeviceToDevice, stream);
    cast4_kernel<<<dim3(512, 4), 256, 0, stream>>>(
        ff_w2, ff2w, 256*1024, pw1_w, pw1w, 1024*256,
        pw2_w, pw2w, 256*512,  enc,   encb, 2048*256);
    castT5_kernel<<<dim3(16, 5), 256, 0, stream>>>(
        q_w, k_w, v_w, pos_w, out_w, qkvw, kw, vw, posw, outw);
    castFF1_kernel<<<3072, 256, 0, stream>>>(ff_w1, ff1w);

    // --- FeedForward ---
    ln_kernel<<<MBT/4, 256, 0, stream>>>(x, ff_ln_g, ff_ln_b, lnbuf);
    gemm_bf<64,128,1,true,true,false,true><<<dim3(FFI_/128, MBT/64), 256, 0, stream>>>(
        lnbuf, ff1w, ff_b1, nullptr, y1bf, MBT, FFI_, 3*D_, 0.f, zbuf);
    gemm_bf<64,64,0,true,false,true,false><<<dim3(D_/64, MBT/64), 256, 0, stream>>>(
        y1bf, ff2w, ff_b2, x, x1, MBT, D_, FFI_, 0.5f, nullptr);

    // --- Relative MHSA ---
    ln_kernel<<<MBT/4, 256, 0, stream>>>(x1, at_ln_g, at_ln_b, lnbuf);
    gemm_bf<128,64,0,true,false,false,true><<<dim3(768/64, MBT/128), 256, 0, stream>>>(
        lnbuf, qkvw, qkv_bias, nullptr, qkv, MBT, 768, D_, 0.f, nullptr);
    gemm_bf<128,64,0,false,false,false,true><<<dim3(D_/64, T_/128), 256, 0, stream>>>(
        encb, posw, nullptr, nullptr, posb, T_, D_, D_, 0.f, nullptr);
    vT_kernel<<<dim3(T_/64, D_/64, B_), 256, 0, stream>>>(qkv, vbT);
    attn11_kernel<<<dim3(T_/128, B_*H_, 2), 512, 0, stream>>>(
        qkv, vbT, posb, u_bias, v_bias, Op, ml, zbuf);
    amerge_kernel<<<(32768 * 16) / 256, 256, 0, stream>>>(Op, ml, ctxb);
    gemm_bf<64,64,0,true,false,true,false><<<dim3(D_/64, MBT/64), 256, 0, stream>>>(
        ctxb, outw, out_b, x1, x2, MBT, D_, D_, 1.f, nullptr);

    // --- Conformer conv module ---
    ln_kernel<<<MBT/4, 256, 0, stream>>>(x2, cm_ln_g, cm_ln_b, lnbuf);
    gemm_bf<64,128,0,true,false,false,true><<<dim3(FFI_/128, MBT/64), 256, 0, stream>>>(
        lnbuf, pw1w, pw1_b, nullptr, ypw1, MBT, FFI_, D_, 0.f, nullptr);
    dw2_kernel<<<dim3(T_/TT_, B_), 256, 0, stream>>>(ypw1, dw_w, dw_b, ydw, stats);
    gn_kernel<<<(MBT * INNER_) / (256 * 8), 256, 0, stream>>>(ydw, gn_g, gn_b, stats, gnb);
    gemm_bf<64,64,0,true,false,true,false><<<dim3(D_/64, MBT/64), 256, 0, stream>>>(
        gnb, pw2w, pw2_b, x2, out, MBT, D_, INNER_, 1.f, nullptr);
}

// Round 21
// 338.546 us; speedup vs baseline: 1.0132x; 1.0087x over previous
//
#include <hip/hip_runtime.h>
#include <math.h>

#define B_ 4
#define T_ 2048
#define D_ 256
#define H_ 4
#define DH_ 64
#define INNER_ 512
#define FFI_ 1024

typedef unsigned short u16;
typedef __bf16 bhalf;
typedef bhalf bhalf8 __attribute__((ext_vector_type(8)));
typedef float floatx4 __attribute__((ext_vector_type(4)));

__device__ __forceinline__ float lrelu(float x){ return x >= 0.f ? x : 0.3f * x; }

// native RTNE bf16 convert (v_cvt_pk_bf16_f32)
__device__ __forceinline__ u16 f2b(float f){
    __bf16 h = (__bf16)f;
    return __builtin_bit_cast(unsigned short, h);
}
__device__ __forceinline__ float b2f(u16 v){ return __uint_as_float((unsigned)v << 16); }

__device__ __forceinline__ void gload16(const void* g, void* l){
    __builtin_amdgcn_global_load_lds(
        (const __attribute__((address_space(1))) unsigned*)g,
        (__attribute__((address_space(3))) unsigned*)l, 16, 0, 0);
}

// ---- DPP 16-lane rotate-reduce (row_ror:1/2/4/8), pure VALU, no LDS pipe ----
__device__ __forceinline__ float dpp16_add(float x){
    int t;
    t = __builtin_amdgcn_update_dpp(0, __float_as_int(x), 0x121, 0xf, 0xf, false); x += __int_as_float(t);
    t = __builtin_amdgcn_update_dpp(0, __float_as_int(x), 0x122, 0xf, 0xf, false); x += __int_as_float(t);
    t = __builtin_amdgcn_update_dpp(0, __float_as_int(x), 0x124, 0xf, 0xf, false); x += __int_as_float(t);
    t = __builtin_amdgcn_update_dpp(0, __float_as_int(x), 0x128, 0xf, 0xf, false); x += __int_as_float(t);
    return x;
}
__device__ __forceinline__ float dpp16_max(float x){
    int t;
    t = __builtin_amdgcn_update_dpp(0, __float_as_int(x), 0x121, 0xf, 0xf, false); x = fmaxf(x, __int_as_float(t));
    t = __builtin_amdgcn_update_dpp(0, __float_as_int(x), 0x122, 0xf, 0xf, false); x = fmaxf(x, __int_as_float(t));
    t = __builtin_amdgcn_update_dpp(0, __float_as_int(x), 0x124, 0xf, 0xf, false); x = fmaxf(x, __int_as_float(t));
    t = __builtin_amdgcn_update_dpp(0, __float_as_int(x), 0x128, 0xf, 0xf, false); x = fmaxf(x, __int_as_float(t));
    return x;
}

// ------------- weight/activation cast kernels (float4-vectorized) -------------
__global__ __launch_bounds__(256) void cast4_kernel(
        const float* __restrict__ s0, u16* d0, int n0_,
        const float* __restrict__ s1, u16* d1, int n1_,
        const float* __restrict__ s2, u16* d2, int n2_,
        const float* __restrict__ s3, u16* d3, int n3_){
    int idx4 = (blockIdx.x * 256 + threadIdx.x) * 4;
    int y = blockIdx.y;
    const float* s = y==0 ? s0 : y==1 ? s1 : y==2 ? s2 : s3;
    u16* d        = y==0 ? d0 : y==1 ? d1 : y==2 ? d2 : d3;
    int n         = y==0 ? n0_ : y==1 ? n1_ : y==2 ? n2_ : n3_;
    if (idx4 < n){                       // n % 4 == 0 for all inputs
        float4 v = *(const float4*)(s + idx4);
        ushort4 o;
        o.x = f2b(v.x); o.y = f2b(v.y); o.z = f2b(v.z); o.w = f2b(v.w);
        *(ushort4*)(d + idx4) = o;
    }
}

// 256x256 transpose-cast via LDS tile (vT-proven pattern):
// d[n][k] = bf16(s[k][n]); coalesced float4 reads + float4 writes.
__global__ __launch_bounds__(256) void castT5_kernel(
        const float* __restrict__ s0, const float* __restrict__ s1,
        const float* __restrict__ s2, const float* __restrict__ s3,
        const float* __restrict__ s4,
        u16* d0, u16* d1, u16* d2, u16* d3, u16* d4){
    __shared__ u16 tile[64 * 68];
    int y = blockIdx.y;
    const float* s = y==0 ? s0 : y==1 ? s1 : y==2 ? s2 : y==3 ? s3 : s4;
    u16* d        = y==0 ? d0 : y==1 ? d1 : y==2 ? d2 : y==3 ? d3 : d4;
    int k0 = (blockIdx.x & 3) * 64, n0 = (blockIdx.x >> 2) * 64;
    int tid = threadIdx.x;
    // load: tile[k][n] <- bf16(s[k0+k][n0+n]), 4 f32 per thread pass
    for (int u = tid; u < 1024; u += 256){
        int r = u >> 4, c4 = (u & 15) * 4;
        float4 v = *(const float4*)(s + (size_t)(k0 + r) * 256 + n0 + c4);
        u16 o4[4];
        o4[0] = f2b(v.x); o4[1] = f2b(v.y); o4[2] = f2b(v.z); o4[3] = f2b(v.w);
        *(uint2*)&tile[r * 68 + c4] = *(uint2*)o4;
    }
    __syncthreads();
    // write: d[n0+n][k0+k] <- tile[k][n], 8 u16 per thread pass
    for (int u = tid; u < 512; u += 256){
        int n = u >> 3, k8 = (u & 7) * 8;
        u16 g[8];
        #pragma unroll
        for (int j = 0; j < 8; j++) g[j] = tile[(k8 + j) * 68 + n];
        *(float4*)(d + (size_t)(n0 + n) * 256 + k0 + k8) = *(float4*)g;
    }
}

__global__ __launch_bounds__(256) void castFF1_kernel(const float* __restrict__ s, u16* d){
    int idx = blockIdx.x * 256 + threadIdx.x;
    int n = idx / 768, rem = idx - n * 768;
    int kc = rem >> 8, c = rem & 255;
    d[idx] = f2b(s[(n * 256 + c) * 3 + kc]);
}

// ---------------- LayerNorm: one wave per 256-elem row ----------------
__global__ __launch_bounds__(256) void ln_kernel(const float* __restrict__ x,
        const float* __restrict__ g, const float* __restrict__ b,
        u16* __restrict__ out){
    int wave = threadIdx.x >> 6, lane = threadIdx.x & 63;
    int row = blockIdx.x * 4 + wave;
    size_t base = (size_t)row * D_ + lane * 4;
    float4 v = *(const float4*)(x + base);
    float s = v.x + v.y + v.z + v.w;
    #pragma unroll
    for (int mk = 1; mk < 64; mk <<= 1) s += __shfl_xor(s, mk, 64);
    float mean = s * (1.f / D_);
    float4 d = make_float4(v.x - mean, v.y - mean, v.z - mean, v.w - mean);
    float q = d.x*d.x + d.y*d.y + d.z*d.z + d.w*d.w;
    #pragma unroll
    for (int mk = 1; mk < 64; mk <<= 1) q += __shfl_xor(q, mk, 64);
    float rs = rsqrtf(q * (1.f / D_) + 1e-5f);
    float4 gg = *(const float4*)(g + lane * 4);
    float4 bb = *(const float4*)(b + lane * 4);
    ushort4 o;
    o.x = f2b(d.x * rs * gg.x + bb.x);
    o.y = f2b(d.y * rs * gg.y + bb.y);
    o.z = f2b(d.z * rs * gg.z + bb.z);
    o.w = f2b(d.w * rs * gg.w + bb.w);
    *(ushort4*)(out + base) = o;
}

// ===== bf16 MFMA GEMM, BK=64, XOR-swizzled LDS (conflict-free b128 reads) =====
// Wave tilings: 128x128 (4 waves, 64x64 each), 128x64 (4 waves, 32x64),
// 64x64 (4 waves, 32x32), 64x128 (4 waves, 32x64 each).
// VOUT: blocks with n0>=512 write their output TRANSPOSED to Cv as
// vbT[(b*256 + n-512)*T + t] (4 consecutive t per thread -> ushort4) --
// absorbs the old vT_kernel copy pass into the qkv-projection epilogue.
template<int BM, int BN, int AMODE, bool BIAS, bool ACT, bool RES, bool OUTBF, bool VOUT>
__global__ __launch_bounds__(256) void gemm_bf(
        const u16* __restrict__ A, const u16* __restrict__ Bw,
        const float* __restrict__ bias, const float* __restrict__ res,
        void* __restrict__ C, int M, int N, int K, float alpha,
        const u16* __restrict__ zbuf, u16* __restrict__ Cv){
    __shared__ __align__(16) u16 As[BM * 64];
    __shared__ __align__(16) u16 Bs[BN * 64];
    const int tid = threadIdx.x;
    const int lane = tid & 63, w = tid >> 6;
    const int ln15 = lane & 15, quad = lane >> 4;
    const int lsw = ln15 & 7;
    const int m0 = blockIdx.y * BM, n0 = blockIdx.x * BN;
    const int srow8 = lane >> 3;                 // row within 8-row stage chunk
    const int swzc  = ((lane & 7) ^ srow8) * 8;  // pre-swizzled source col (u16)
    const bool M64N128 = (BM == 64 && BN == 128);
    const int MT = (BM == 64) ? 2 : ((BN == 128) ? 4 : 2);
    const int NT = M64N128 ? 4 : ((BM == 64) ? 2 : 4);
    const int wm = M64N128 ? (w & 1) : ((BM == 64 || BN == 128) ? (w >> 1) : w);
    const int wn = M64N128 ? (w >> 1) : ((BM == 64 || BN == 128) ? (w & 1) : 0);
    const int mbase = M64N128 ? wm * 32
                     : ((BM == 64) ? wm * 32 : ((BN == 128) ? wm * 64 : w * 32));
    const int nbase = M64N128 ? wn * 64
                     : ((BM == 64) ? wn * 32 : ((BN == 128) ? wn * 64 : 0));
    const int JA = BM / 32;                      // A stage gloads per wave
    const int JB = BN / 32;

    floatx4 acc[4][4];
    #pragma unroll
    for (int i = 0; i < 4; i++)
        #pragma unroll
        for (int j = 0; j < 4; j++)
            acc[i][j] = (floatx4){0.f, 0.f, 0.f, 0.f};

    for (int k0 = 0; k0 < K; k0 += 64){
        __syncthreads();
        #pragma unroll
        for (int j = 0; j < JA; j++){
            int mrow = m0 + w * (BM / 4) + j * 8 + srow8;
            const u16* ga;
            if (AMODE == 0){
                ga = A + (size_t)mrow * K + k0 + swzc;
            } else {
                int bb = mrow >> 11, t = mrow & (T_ - 1);
                int kc = k0 >> 8;
                int c = (k0 & 255) + swzc;        // swzc<64, k0%64==0 -> no 256-cross
                int t2 = t + kc - 1;
                ga = ((unsigned)t2 < (unsigned)T_)
                     ? A + ((size_t)(bb * T_ + t2)) * D_ + c : zbuf;
            }
            gload16(ga, &As[(w * (BM / 4) + j * 8) * 64]);
        }
        #pragma unroll
        for (int j = 0; j < JB; j++){
            const u16* gb = Bw + (size_t)(n0 + w * (BN / 4) + j * 8 + srow8) * K + k0 + swzc;
            gload16(gb, &Bs[(w * (BN / 4) + j * 8) * 64]);
        }
        __syncthreads();
        #pragma unroll
        for (int ks = 0; ks < 2; ks++){
            const int rc = (((ks << 2) + quad) ^ lsw) * 8;
            bhalf8 af[4], bfr[4];
            #pragma unroll
            for (int mi = 0; mi < MT; mi++)
                af[mi] = *(const bhalf8*)&As[(mbase + mi * 16 + ln15) * 64 + rc];
            #pragma unroll
            for (int ni = 0; ni < NT; ni++)
                bfr[ni] = *(const bhalf8*)&Bs[(nbase + ni * 16 + ln15) * 64 + rc];
            #pragma unroll
            for (int mi = 0; mi < MT; mi++)
                #pragma unroll
                for (int ni = 0; ni < NT; ni++)
                    acc[mi][ni] = __builtin_amdgcn_mfma_f32_16x16x32_bf16(
                        af[mi], bfr[ni], acc[mi][ni], 0, 0, 0);
        }
    }
    if (VOUT && n0 >= 512){
        // V-projection blocks: write transposed directly into vbT layout.
        #pragma unroll
        for (int mi = 0; mi < MT; mi++){
            #pragma unroll
            for (int ni = 0; ni < NT; ni++){
                int n = n0 + nbase + ni * 16 + ln15;
                float bv = BIAS ? bias[n] : 0.f;
                int mbeg = m0 + mbase + mi * 16 + quad * 4;   // 4 consecutive t
                int bb = mbeg >> 11, tt = mbeg & (T_ - 1);
                u16 o4[4];
                #pragma unroll
                for (int r = 0; r < 4; r++) o4[r] = f2b(acc[mi][ni][r] + bv);
                *(ushort4*)(Cv + ((size_t)(bb * 256 + (n - 512))) * T_ + tt) = *(ushort4*)o4;
            }
        }
        return;
    }
    #pragma unroll
    for (int mi = 0; mi < MT; mi++){
        #pragma unroll
        for (int ni = 0; ni < NT; ni++){
            int n = n0 + nbase + ni * 16 + ln15;
            float bv = BIAS ? bias[n] : 0.f;
            #pragma unroll
            for (int r = 0; r < 4; r++){
                int m = m0 + mbase + mi * 16 + quad * 4 + r;
                float val = acc[mi][ni][r] + bv;
                if (ACT) val = lrelu(val);
                if (RES) val = res[(size_t)m * N + n] + alpha * val;
                if (OUTBF) ((u16*)C)[(size_t)m * N + n] = f2b(val);
                else       ((float*)C)[(size_t)m * N + n] = val;
            }
        }
    }
}

// ========== 8-wave QBLK=128 flash attention, gload_lds staging + XOR swizzle ==========
// (round-4..19 HW-verified structure; Op partials stored bf16, merge math f32)
__global__ __launch_bounds__(512) void attn11_kernel(
        const u16* __restrict__ qkv, const u16* __restrict__ vbT,
        const u16* __restrict__ posb,
        const float* __restrict__ ub, const float* __restrict__ vbias,
        u16* __restrict__ Op, float* __restrict__ ml,
        const u16* __restrict__ zbuf)
{
    __shared__ __align__(16) u16 Ks[64 * 64];
    __shared__ __align__(16) u16 Vs[64 * 64];
    __shared__ __align__(16) u16 Pos[192 * 64];
    __shared__ __align__(16) u16 Pb[8 * 16 * 90];

    const int tid = threadIdx.x;
    const int lane = tid & 63, w = tid >> 6;
    const int ln15 = lane & 15, quad = lane >> 4;
    const int lsw = ln15 & 7;                 // read-side XOR key (row&7 == ln15&7)

    // XCD-locality swizzle: 512 = 8 xcd * 2 bh * 2 z * 16 t-blocks (bijective)
    int wgid = blockIdx.x + 16 * (blockIdx.y + 16 * blockIdx.z);
    int xcd = wgid & 7, idx = wgid >> 3;               // idx in [0,64)
    const int bh = xcd * 2 + (idx >> 5);
    const int z  = (idx >> 4) & 1;
    const int t0 = (idx & 15) * 128;
    const int b = bh >> 2, h = bh & 3;

    const u16* qg  = qkv + (size_t)b * T_ * 768 + h * DH_;
    const u16* kg  = qkv + (size_t)b * T_ * 768 + 256 + h * DH_;
    const u16* vtg = vbT + ((size_t)(b * 256 + h * DH_)) * T_;
    const u16* pg  = posb + h * DH_;

    // staging geometry: wave w stages rows [w*8, w*8+8); lane -> (row, chunk)
    const int srow8 = lane >> 3;              // row within the wave's 8-row strip
    const int swz8  = (lane & 7) ^ srow8;     // pre-swizzled source chunk * 8 u16
    const int srowg = w * 8 + srow8;          // row within 64-row tile

    // ---- register Q fragments (wave w owns q-rows t0+w*16 .. +15) ----
    bhalf8 quf[2], qvf0[2], qvf1[2];
    {
        int qrow = t0 + w * 16 + ln15;
        #pragma unroll
        for (int ks = 0; ks < 2; ks++){
            int dof = ks * 32 + quad * 8;
            u16 q8[8];
            *(float4*)q8 = *(const float4*)(qg + (size_t)qrow * 768 + dof);
            u16 q8n[8] = {0,0,0,0,0,0,0,0};
            if (qrow + 1 < T_)
                *(float4*)q8n = *(const float4*)(qg + (size_t)(qrow + 1) * 768 + dof);
            u16 a[8], c0[8], c1[8];
            #pragma unroll
            for (int j = 0; j < 8; j++){
                float uu = ub[h * DH_ + dof + j];
                float vv = vbias[h * DH_ + dof + j];
                float qf = b2f(q8[j]), qf1 = b2f(q8n[j]);
                a[j]  = f2b(qf + uu);
                c0[j] = f2b(qf + vv);
                c1[j] = f2b(qf1 + vv);
            }
            quf[ks]  = *(bhalf8*)a;
            qvf0[ks] = *(bhalf8*)c0;
            qvf1[ks] = *(bhalf8*)c1;
        }
    }

    floatx4 O[4];
    #pragma unroll
    for (int i = 0; i < 4; i++) O[i] = (floatx4){0.f,0.f,0.f,0.f};
    float m_r[4], l_r[4];
    #pragma unroll
    for (int r = 0; r < 4; r++){ m_r[r] = -INFINITY; l_r[r] = 0.f; }

    u16* pbw = Pb + w * 16 * 90;
    const int prow0 = (7 - w) * 16 + ln15;   // band row base (127-offset space)

    int s0 = z * (T_ / 2);
    for (int it = 0; it < 16; it++, s0 += 64){
        const int diff = s0 - t0;
        __syncthreads();   // barrier 1: previous tile fully consumed
        // ---- stage K, V, Pos via global_load_lds (pre-swizzled source) ----
        {
            gload16(kg + (size_t)(s0 + srowg) * 768 + swz8 * 8, &Ks[(w * 8) * 64]);
            gload16(vtg + (size_t)srowg * T_ + s0 + swz8 * 8,  &Vs[(w * 8) * 64]);
            int jb = (diff <= 64) ? (T_ - 128 + diff) : (diff - 129);
            #pragma unroll
            for (int j = 0; j < 3; j++){
                int jj = jb + j * 64 + srowg;
                const u16* ga = ((unsigned)jj < (unsigned)T_)
                                ? pg + (size_t)jj * D_ + swz8 * 8 : zbuf;
                gload16(ga, &Pos[(j * 64 + w * 8) * 64]);
            }
        }
        __syncthreads();   // barrier 2: tile ready (barrier drains vmcnt)

        // ---- band first (keeps Bacc/S from being co-live) ----
        floatx4 Bacc[5];
        #pragma unroll
        for (int i = 0; i < 5; i++) Bacc[i] = (floatx4){0.f,0.f,0.f,0.f};
        #pragma unroll
        for (int ks = 0; ks < 2; ks++){
            bhalf8 av = (diff <= 64) ? qvf0[ks] : qvf1[ks];
            #pragma unroll
            for (int n5 = 0; n5 < 5; n5++){
                bhalf8 bf = *(const bhalf8*)&Pos[(prow0 + n5 * 16) * 64
                                                 + (((ks << 2) + quad) ^ lsw) * 8];
                Bacc[n5] = __builtin_amdgcn_mfma_f32_16x16x32_bf16(av, bf, Bacc[n5], 0, 0, 0);
            }
        }
        if (diff == 0 || diff == 64){
            // mixed diagonal tile: s>t half via direct-global pos fragments
            int jb2 = diff - 129;
            #pragma unroll
            for (int ks = 0; ks < 2; ks++){
                #pragma unroll
                for (int n5 = 0; n5 < 5; n5++){
                    int jj = jb2 + prow0 + n5 * 16;
                    const u16* pp = ((unsigned)jj < (unsigned)T_)
                        ? pg + (size_t)jj * D_ + ks * 32 + quad * 8 : zbuf;
                    Bacc[n5] = __builtin_amdgcn_mfma_f32_16x16x32_bf16(qvf1[ks], *(const bhalf8*)pp,
                                                                       Bacc[n5], 0, 0, 0);
                }
            }
        }
        // ---- wave-local band strip write (Bacc dies here) ----
        #pragma unroll
        for (int n5 = 0; n5 < 5; n5++)
            #pragma unroll
            for (int r = 0; r < 4; r++)
                pbw[(quad * 4 + r) * 90 + n5 * 16 + ln15] = f2b(Bacc[n5][r]);

        // ---- QK ----
        floatx4 S[4];
        #pragma unroll
        for (int i = 0; i < 4; i++) S[i] = (floatx4){0.f,0.f,0.f,0.f};
        #pragma unroll
        for (int ks = 0; ks < 2; ks++){
            #pragma unroll
            for (int nt = 0; nt < 4; nt++){
                bhalf8 bf = *(const bhalf8*)&Ks[(nt * 16 + ln15) * 64
                                                + (((ks << 2) + quad) ^ lsw) * 8];
                S[nt] = __builtin_amdgcn_mfma_f32_16x16x32_bf16(quf[ks], bf, S[nt], 0, 0, 0);
            }
        }
        // ---- shifted band read + score ----
        float sc[4][4];
        #pragma unroll
        for (int nt = 0; nt < 4; nt++)
            #pragma unroll
            for (int r = 0; r < 4; r++){
                int i = quad * 4 + r;
                int c = nt * 16 + ln15 + 15 - i;
                sc[nt][r] = (S[nt][r] + b2f(pbw[i * 90 + c])) * 0.0625f;
            }
        // ---- online softmax (__expf), DPP reductions ----
        #pragma unroll
        for (int r = 0; r < 4; r++){
            float rowm = fmaxf(fmaxf(sc[0][r], sc[1][r]), fmaxf(sc[2][r], sc[3][r]));
            rowm = dpp16_max(rowm);
            float mnew = fmaxf(m_r[r], rowm);
            float alpha = __expf(m_r[r] - mnew);
            float rs = 0.f;
            #pragma unroll
            for (int nt = 0; nt < 4; nt++){ sc[nt][r] = __expf(sc[nt][r] - mnew); rs += sc[nt][r]; }
            rs = dpp16_add(rs);
            l_r[r] = l_r[r] * alpha + rs;
            m_r[r] = mnew;
            O[0][r] *= alpha; O[1][r] *= alpha; O[2][r] *= alpha; O[3][r] *= alpha;
        }
        #pragma unroll
        for (int nt = 0; nt < 4; nt++)
            #pragma unroll
            for (int r = 0; r < 4; r++)
                pbw[(quad * 4 + r) * 90 + nt * 16 + ln15] = f2b(sc[nt][r]);
        // ---- PV (strip is wave-private: no barrier needed) ----
        #pragma unroll
        for (int ks = 0; ks < 2; ks++){
            bhalf8 af = *(const bhalf8*)&pbw[ln15 * 90 + ks * 32 + quad * 8];
            #pragma unroll
            for (int nt = 0; nt < 4; nt++){
                bhalf8 bf = *(const bhalf8*)&Vs[(nt * 16 + ln15) * 64
                                                + (((ks << 2) + quad) ^ lsw) * 8];
                O[nt] = __builtin_amdgcn_mfma_f32_16x16x32_bf16(af, bf, O[nt], 0, 0, 0);
            }
        }
    }
    #pragma unroll
    for (int r = 0; r < 4; r++){
        int t = t0 + w * 16 + quad * 4 + r;
        size_t row = (size_t)(z * 32768 + bh * 2048 + t);
        #pragma unroll
        for (int nt = 0; nt < 4; nt++)
            Op[row * 64 + nt * 16 + ln15] = f2b(O[nt][r]);
        if (ln15 == 0){
            ml[row * 2 + 0] = m_r[r];
            ml[row * 2 + 1] = l_r[r];
        }
    }
}

// ------------- merge split-K attention partials (bf16 partials, f32 math) -------------
__global__ __launch_bounds__(256) void amerge_kernel(const u16* __restrict__ Op,
        const float* __restrict__ ml, u16* __restrict__ ctx){
    int gid = blockIdx.x * 256 + threadIdx.x;
    int row = gid >> 4, d4 = (gid & 15) * 4;
    int bh = row >> 11, t = row & 2047;
    int b = bh >> 2, h = bh & 3;
    float m1 = ml[(size_t)row * 2], l1 = ml[(size_t)row * 2 + 1];
    float m2 = ml[(size_t)(32768 + row) * 2], l2 = ml[(size_t)(32768 + row) * 2 + 1];
    float m = fmaxf(m1, m2);
    float a1 = __expf(m1 - m), a2 = __expf(m2 - m);
    float invl = 1.f / (l1 * a1 + l2 * a2);
    u16 p1[4], p2[4];
    *(ushort4*)p1 = *(const ushort4*)(Op + (size_t)row * 64 + d4);
    *(ushort4*)p2 = *(const ushort4*)(Op + (size_t)(32768 + row) * 64 + d4);
    ushort4 o;
    o.x = f2b((b2f(p1[0]) * a1 + b2f(p2[0]) * a2) * invl);
    o.y = f2b((b2f(p1[1]) * a1 + b2f(p2[1]) * a2) * invl);
    o.z = f2b((b2f(p1[2]) * a1 + b2f(p2[2]) * a2) * invl);
    o.w = f2b((b2f(p1[3]) * a1 + b2f(p2[3]) * a2) * invl);
    *(ushort4*)(ctx + ((size_t)(b * T_ + t)) * D_ + h * DH_ + d4) = o;
}

// ------- depthwise conv K=7, fused GLU tile-load, wave-reduced GN stats -------
#define TT_ 32
__global__ __launch_bounds__(256) void dw2_kernel(const u16* __restrict__ ypw1,
        const float* __restrict__ w, const float* __restrict__ bias,
        u16* __restrict__ y, float* __restrict__ stats){
    __shared__ u16 tile[(TT_ + 6) * INNER_];
    int tid = threadIdx.x;
    int t0 = blockIdx.x * TT_, b = blockIdx.y;
    for (int uu = tid; uu < (TT_ + 6) * 64; uu += 256){
        int row = uu >> 6, c8 = (uu & 63) * 8;
        int t = t0 + row - 3;
        u16 o8[8] = {0,0,0,0,0,0,0,0};
        if ((unsigned)t < (unsigned)T_){
            u16 a8[8], g8[8];
            const u16* rp = ypw1 + ((size_t)(b * T_ + t)) * 1024;
            *(float4*)a8 = *(const float4*)(rp + c8);
            *(float4*)g8 = *(const float4*)(rp + 512 + c8);
            #pragma unroll
            for (int j = 0; j < 8; j++) o8[j] = f2b(b2f(a8[j]) * lrelu(b2f(g8[j])));
        }
        *(float4*)&tile[row * INNER_ + c8] = *(float4*)o8;
    }
    __syncthreads();
    int c8 = (tid & 63) * 8, trow = tid >> 6;
    float wreg[7][8], bv[8];
    #pragma unroll
    for (int j = 0; j < 8; j++){
        bv[j] = bias[c8 + j];
        #pragma unroll
        for (int kk = 0; kk < 7; kk++) wreg[kk][j] = w[(c8 + j) * 7 + kk];
    }
    float s1 = 0.f, s2 = 0.f;
    for (int tt = trow; tt < TT_; tt += 4){
        float acc[8];
        #pragma unroll
        for (int j = 0; j < 8; j++) acc[j] = bv[j];
        #pragma unroll
        for (int kk = 0; kk < 7; kk++){
            u16 r8[8];
            *(float4*)r8 = *(const float4*)&tile[(tt + kk) * INNER_ + c8];
            #pragma unroll
            for (int j = 0; j < 8; j++) acc[j] += b2f(r8[j]) * wreg[kk][j];
        }
        u16 o8[8];
        #pragma unroll
        for (int j = 0; j < 8; j++) o8[j] = f2b(acc[j]);
        *(float4*)(y + ((size_t)(b * T_ + t0 + tt)) * INNER_ + c8) = *(float4*)o8;
        #pragma unroll
        for (int j = 0; j < 8; j++){ s1 += acc[j]; s2 += acc[j] * acc[j]; }
    }
    #pragma unroll
    for (int mk = 1; mk < 64; mk <<= 1){
        s1 += __shfl_xor(s1, mk, 64);
        s2 += __shfl_xor(s2, mk, 64);
    }
    if ((tid & 63) == 0){
        atomicAdd(&stats[b * 2], s1);
        atomicAdd(&stats[b * 2 + 1], s2);
    }
}

// ---------------- GroupNorm(1) apply + leaky, bf16 in/out ----------------
__global__ __launch_bounds__(256) void gn_kernel(const u16* __restrict__ y,
        const float* __restrict__ g, const float* __restrict__ b2,
        const float* __restrict__ stats, u16* __restrict__ out){
    int idx8 = (blockIdx.x * 256 + threadIdx.x) * 8;
    int b = idx8 / (T_ * INNER_);
    int i = idx8 & (INNER_ - 1);
    const float invN = 1.f / (float)(T_ * INNER_);
    float mean = stats[b * 2] * invN;
    float var  = stats[b * 2 + 1] * invN - mean * mean;
    float rs = rsqrtf(var + 1e-5f);
    u16 v8[8], o8[8];
    *(float4*)v8 = *(const float4*)(y + idx8);
    #pragma unroll
    for (int j = 0; j < 8; j++)
        o8[j] = f2b(lrelu((b2f(v8[j]) - mean) * rs * g[i + j] + b2[i + j]));
    *(float4*)(out + idx8) = *(float4*)o8;
}

extern "C" void kernel_launch(void* const* d_in, const int* in_sizes, int n_in,
                              void* d_out, int out_size, void* d_ws, size_t ws_size,
                              hipStream_t stream){
    const float* x        = (const float*)d_in[0];
    const float* enc      = (const float*)d_in[1];
    const float* ff_ln_g  = (const float*)d_in[3];
    const float* ff_ln_b  = (const float*)d_in[4];
    const float* ff_w1    = (const float*)d_in[5];
    const float* ff_b1    = (const float*)d_in[6];
    const float* ff_w2    = (const float*)d_in[7];
    const float* ff_b2    = (const float*)d_in[8];
    const float* at_ln_g  = (const float*)d_in[9];
    const float* at_ln_b  = (const float*)d_in[10];
    const float* q_w      = (const float*)d_in[11];
    const float* q_b      = (const float*)d_in[12];
    const float* k_w      = (const float*)d_in[13];
    const float* v_w      = (const float*)d_in[14];
    const float* pos_w    = (const float*)d_in[15];
    const float* u_bias   = (const float*)d_in[16];
    const float* v_bias   = (const float*)d_in[17];
    const float* out_w    = (const float*)d_in[18];
    const float* out_b    = (const float*)d_in[19];
    const float* cm_ln_g  = (const float*)d_in[20];
    const float* cm_ln_b  = (const float*)d_in[21];
    const float* pw1_w    = (const float*)d_in[22];
    const float* pw1_b    = (const float*)d_in[23];
    const float* dw_w     = (const float*)d_in[24];
    const float* dw_b     = (const float*)d_in[25];
    const float* gn_g     = (const float*)d_in[26];
    const float* gn_b     = (const float*)d_in[27];
    const float* pw2_w    = (const float*)d_in[28];
    const float* pw2_b    = (const float*)d_in[29];
    float* out = (float*)d_out;

    char* ws = (char*)d_ws;
    u16*   y1bf = (u16*)(ws + 0);
    u16*   ypw1 = (u16*)(ws + 0);
    u16*   Op   = (u16*)(ws + 0);
    float* ml   = (float*)(ws + ((size_t)16 << 20));
    u16*   ydw  = (u16*)(ws + ((size_t)16 << 20));
    u16*   qkv  = (u16*)(ws + ((size_t)32 << 20));
    u16*   vbT  = (u16*)(ws + ((size_t)44 << 20));
    u16*   ctxb = (u16*)(ws + ((size_t)48 << 20));
    u16*   posb = (u16*)(ws + ((size_t)52 << 20));
    u16*   lnbuf= (u16*)(ws + ((size_t)53 << 20));
    float* x1   = (float*)(ws + ((size_t)57 << 20));
    float* x2   = (float*)(ws + ((size_t)65 << 20));
    u16*   gnb  = (u16*)(ws + ((size_t)36 << 20));
    char* W = ws + ((size_t)81 << 20);
    u16* ff1w  = (u16*)(W);
    u16* ff2w  = (u16*)(W + ((size_t)2 << 20));
    u16* qkvw  = (u16*)(W + ((size_t)3 << 20));
    u16* kw    = qkvw + 65536;
    u16* vw    = qkvw + 131072;
    u16* posw  = (u16*)(W + ((size_t)3 << 20) + (384u << 10));
    u16* outw  = (u16*)(W + ((size_t)4 << 20));
    u16* pw1w  = (u16*)(W + ((size_t)5 << 20));
    u16* pw2w  = (u16*)(W + ((size_t)6 << 20));
    u16* encb  = (u16*)(W + ((size_t)7 << 20));
    u16* zbuf  = (u16*)(W + ((size_t)8 << 20));
    float* stats    = (float*)(W + ((size_t)8 << 20) + 4096);
    float* qkv_bias = (float*)(W + ((size_t)8 << 20) + 8192);

    const int MBT = B_ * T_;

    hipMemsetAsync(W + ((size_t)8 << 20), 0, 16384, stream);
    hipMemcpyAsync(qkv_bias, q_b, 256 * sizeof(float), hipMemcpyDeviceToDevice, stream);
    cast4_kernel<<<dim3(512, 4), 256, 0, stream>>>(
        ff_w2, ff2w, 256*1024, pw1_w, pw1w, 1024*256,
        pw2_w, pw2w, 256*512,  enc,   encb, 2048*256);
    castT5_kernel<<<dim3(16, 5), 256, 0, stream>>>(
        q_w, k_w, v_w, pos_w, out_w, qkvw, kw, vw, posw, outw);
    castFF1_kernel<<<3072, 256, 0, stream>>>(ff_w1, ff1w);

    // --- FeedForward ---
    ln_kernel<<<MBT/4, 256, 0, stream>>>(x, ff_ln_g, ff_ln_b, lnbuf);
    gemm_bf<64,128,1,true,true,false,true,false><<<dim3(FFI_/128, MBT/64), 256, 0, stream>>>(
        lnbuf, ff1w, ff_b1, nullptr, y1bf, MBT, FFI_, 3*D_, 0.f, zbuf, nullptr);
    gemm_bf<64,64,0,true,false,true,false,false><<<dim3(D_/64, MBT/64), 256, 0, stream>>>(
        y1bf, ff2w, ff_b2, x, x1, MBT, D_, FFI_, 0.5f, nullptr, nullptr);

    // --- Relative MHSA ---
    ln_kernel<<<MBT/4, 256, 0, stream>>>(x1, at_ln_g, at_ln_b, lnbuf);
    gemm_bf<128,64,0,true,false,false,true,true><<<dim3(768/64, MBT/128), 256, 0, stream>>>(
        lnbuf, qkvw, qkv_bias, nullptr, qkv, MBT, 768, D_, 0.f, nullptr, vbT);
    gemm_bf<128,64,0,false,false,false,true,false><<<dim3(D_/64, T_/128), 256, 0, stream>>>(
        encb, posw, nullptr, nullptr, posb, T_, D_, D_, 0.f, nullptr, nullptr);
    attn11_kernel<<<dim3(T_/128, B_*H_, 2), 512, 0, stream>>>(
        qkv, vbT, posb, u_bias, v_bias, Op, ml, zbuf);
    amerge_kernel<<<(32768 * 16) / 256, 256, 0, stream>>>(Op, ml, ctxb);
    gemm_bf<64,64,0,true,false,true,false,false><<<dim3(D_/64, MBT/64), 256, 0, stream>>>(
        ctxb, outw, out_b, x1, x2, MBT, D_, D_, 1.f, nullptr, nullptr);

    // --- Conformer conv module ---
    ln_kernel<<<MBT/4, 256, 0, stream>>>(x2, cm_ln_g, cm_ln_b, lnbuf);
    gemm_bf<64,128,0,true,false,false,true,false><<<dim3(FFI_/128, MBT/64), 256, 0, stream>>>(
        lnbuf, pw1w, pw1_b, nullptr, ypw1, MBT, FFI_, D_, 0.f, nullptr, nullptr);
    dw2_kernel<<<dim3(T_/TT_, B_), 256, 0, stream>>>(ypw1, dw_w, dw_b, ydw, stats);
    gn_kernel<<<(MBT * INNER_) / (256 * 8), 256, 0, stream>>>(ydw, gn_g, gn_b, stats, gnb);
    gemm_bf<64,64,0,true,false,true,false,false><<<dim3(D_/64, MBT/64), 256, 0, stream>>>(
        gnb, pw2w, pw2_b, x2, out, MBT, D_, INNER_, 1.f, nullptr, nullptr);
}

// Round 22
// 335.637 us; speedup vs baseline: 1.0219x; 1.0087x over previous
//
#include <hip/hip_runtime.h>
#include <math.h>

#define B_ 4
#define T_ 2048
#define D_ 256
#define H_ 4
#define DH_ 64
#define INNER_ 512
#define FFI_ 1024

typedef unsigned short u16;
typedef __bf16 bhalf;
typedef bhalf bhalf8 __attribute__((ext_vector_type(8)));
typedef float floatx4 __attribute__((ext_vector_type(4)));

__device__ __forceinline__ float lrelu(float x){ return x >= 0.f ? x : 0.3f * x; }

// native RTNE bf16 convert (v_cvt_pk_bf16_f32)
__device__ __forceinline__ u16 f2b(float f){
    __bf16 h = (__bf16)f;
    return __builtin_bit_cast(unsigned short, h);
}
__device__ __forceinline__ float b2f(u16 v){ return __uint_as_float((unsigned)v << 16); }

__device__ __forceinline__ void gload16(const void* g, void* l){
    __builtin_amdgcn_global_load_lds(
        (const __attribute__((address_space(1))) unsigned*)g,
        (__attribute__((address_space(3))) unsigned*)l, 16, 0, 0);
}

// ---- DPP 16-lane rotate-reduce (row_ror:1/2/4/8), pure VALU, no LDS pipe ----
__device__ __forceinline__ float dpp16_add(float x){
    int t;
    t = __builtin_amdgcn_update_dpp(0, __float_as_int(x), 0x121, 0xf, 0xf, false); x += __int_as_float(t);
    t = __builtin_amdgcn_update_dpp(0, __float_as_int(x), 0x122, 0xf, 0xf, false); x += __int_as_float(t);
    t = __builtin_amdgcn_update_dpp(0, __float_as_int(x), 0x124, 0xf, 0xf, false); x += __int_as_float(t);
    t = __builtin_amdgcn_update_dpp(0, __float_as_int(x), 0x128, 0xf, 0xf, false); x += __int_as_float(t);
    return x;
}
__device__ __forceinline__ float dpp16_max(float x){
    int t;
    t = __builtin_amdgcn_update_dpp(0, __float_as_int(x), 0x121, 0xf, 0xf, false); x = fmaxf(x, __int_as_float(t));
    t = __builtin_amdgcn_update_dpp(0, __float_as_int(x), 0x122, 0xf, 0xf, false); x = fmaxf(x, __int_as_float(t));
    t = __builtin_amdgcn_update_dpp(0, __float_as_int(x), 0x124, 0xf, 0xf, false); x = fmaxf(x, __int_as_float(t));
    t = __builtin_amdgcn_update_dpp(0, __float_as_int(x), 0x128, 0xf, 0xf, false); x = fmaxf(x, __int_as_float(t));
    return x;
}

// ------------- weight/activation cast kernels (float4-vectorized) -------------
__global__ __launch_bounds__(256) void cast4_kernel(
        const float* __restrict__ s0, u16* d0, int n0_,
        const float* __restrict__ s1, u16* d1, int n1_,
        const float* __restrict__ s2, u16* d2, int n2_,
        const float* __restrict__ s3, u16* d3, int n3_){
    int idx4 = (blockIdx.x * 256 + threadIdx.x) * 4;
    int y = blockIdx.y;
    const float* s = y==0 ? s0 : y==1 ? s1 : y==2 ? s2 : s3;
    u16* d        = y==0 ? d0 : y==1 ? d1 : y==2 ? d2 : d3;
    int n         = y==0 ? n0_ : y==1 ? n1_ : y==2 ? n2_ : n3_;
    if (idx4 < n){                       // n % 4 == 0 for all inputs
        float4 v = *(const float4*)(s + idx4);
        ushort4 o;
        o.x = f2b(v.x); o.y = f2b(v.y); o.z = f2b(v.z); o.w = f2b(v.w);
        *(ushort4*)(d + idx4) = o;
    }
}

// 256x256 transpose-cast via LDS tile (vT-proven pattern):
// d[n][k] = bf16(s[k][n]); coalesced float4 reads + float4 writes.
__global__ __launch_bounds__(256) void castT5_kernel(
        const float* __restrict__ s0, const float* __restrict__ s1,
        const float* __restrict__ s2, const float* __restrict__ s3,
        const float* __restrict__ s4,
        u16* d0, u16* d1, u16* d2, u16* d3, u16* d4){
    __shared__ u16 tile[64 * 68];
    int y = blockIdx.y;
    const float* s = y==0 ? s0 : y==1 ? s1 : y==2 ? s2 : y==3 ? s3 : s4;
    u16* d        = y==0 ? d0 : y==1 ? d1 : y==2 ? d2 : y==3 ? d3 : d4;
    int k0 = (blockIdx.x & 3) * 64, n0 = (blockIdx.x >> 2) * 64;
    int tid = threadIdx.x;
    // load: tile[k][n] <- bf16(s[k0+k][n0+n]), 4 f32 per thread pass
    for (int u = tid; u < 1024; u += 256){
        int r = u >> 4, c4 = (u & 15) * 4;
        float4 v = *(const float4*)(s + (size_t)(k0 + r) * 256 + n0 + c4);
        u16 o4[4];
        o4[0] = f2b(v.x); o4[1] = f2b(v.y); o4[2] = f2b(v.z); o4[3] = f2b(v.w);
        *(uint2*)&tile[r * 68 + c4] = *(uint2*)o4;
    }
    __syncthreads();
    // write: d[n0+n][k0+k] <- tile[k][n], 8 u16 per thread pass
    for (int u = tid; u < 512; u += 256){
        int n = u >> 3, k8 = (u & 7) * 8;
        u16 g[8];
        #pragma unroll
        for (int j = 0; j < 8; j++) g[j] = tile[(k8 + j) * 68 + n];
        *(float4*)(d + (size_t)(n0 + n) * 256 + k0 + k8) = *(float4*)g;
    }
}

__global__ __launch_bounds__(256) void castFF1_kernel(const float* __restrict__ s, u16* d){
    int idx = blockIdx.x * 256 + threadIdx.x;
    int n = idx / 768, rem = idx - n * 768;
    int kc = rem >> 8, c = rem & 255;
    d[idx] = f2b(s[(n * 256 + c) * 3 + kc]);
}

// ---------------- LayerNorm: one wave per 256-elem row ----------------
__global__ __launch_bounds__(256) void ln_kernel(const float* __restrict__ x,
        const float* __restrict__ g, const float* __restrict__ b,
        u16* __restrict__ out){
    int wave = threadIdx.x >> 6, lane = threadIdx.x & 63;
    int row = blockIdx.x * 4 + wave;
    size_t base = (size_t)row * D_ + lane * 4;
    float4 v = *(const float4*)(x + base);
    float s = v.x + v.y + v.z + v.w;
    #pragma unroll
    for (int mk = 1; mk < 64; mk <<= 1) s += __shfl_xor(s, mk, 64);
    float mean = s * (1.f / D_);
    float4 d = make_float4(v.x - mean, v.y - mean, v.z - mean, v.w - mean);
    float q = d.x*d.x + d.y*d.y + d.z*d.z + d.w*d.w;
    #pragma unroll
    for (int mk = 1; mk < 64; mk <<= 1) q += __shfl_xor(q, mk, 64);
    float rs = rsqrtf(q * (1.f / D_) + 1e-5f);
    float4 gg = *(const float4*)(g + lane * 4);
    float4 bb = *(const float4*)(b + lane * 4);
    ushort4 o;
    o.x = f2b(d.x * rs * gg.x + bb.x);
    o.y = f2b(d.y * rs * gg.y + bb.y);
    o.z = f2b(d.z * rs * gg.z + bb.z);
    o.w = f2b(d.w * rs * gg.w + bb.w);
    *(ushort4*)(out + base) = o;
}

// ===== bf16 MFMA GEMM, BK=64, XOR-swizzled LDS (conflict-free b128 reads) =====
// Wave tilings: 128x128 (4 waves, 64x64 each), 128x64 (4 waves, 32x64),
// 64x64 (4 waves, 32x32), 64x128 (4 waves, 32x64 each).
// VOUT: blocks with n0>=512 write their output TRANSPOSED to Cv as
// vbT[(b*256 + n-512)*T + t] (4 consecutive t per thread -> ushort4) --
// absorbs the old vT_kernel copy pass into the qkv-projection epilogue.
template<int BM, int BN, int AMODE, bool BIAS, bool ACT, bool RES, bool OUTBF, bool VOUT>
__global__ __launch_bounds__(256) void gemm_bf(
        const u16* __restrict__ A, const u16* __restrict__ Bw,
        const float* __restrict__ bias, const float* __restrict__ res,
        void* __restrict__ C, int M, int N, int K, float alpha,
        const u16* __restrict__ zbuf, u16* __restrict__ Cv){
    __shared__ __align__(16) u16 As[BM * 64];
    __shared__ __align__(16) u16 Bs[BN * 64];
    const int tid = threadIdx.x;
    const int lane = tid & 63, w = tid >> 6;
    const int ln15 = lane & 15, quad = lane >> 4;
    const int lsw = ln15 & 7;
    const int m0 = blockIdx.y * BM, n0 = blockIdx.x * BN;
    const int srow8 = lane >> 3;                 // row within 8-row stage chunk
    const int swzc  = ((lane & 7) ^ srow8) * 8;  // pre-swizzled source col (u16)
    const bool M64N128 = (BM == 64 && BN == 128);
    const int MT = (BM == 64) ? 2 : ((BN == 128) ? 4 : 2);
    const int NT = M64N128 ? 4 : ((BM == 64) ? 2 : 4);
    const int wm = M64N128 ? (w & 1) : ((BM == 64 || BN == 128) ? (w >> 1) : w);
    const int wn = M64N128 ? (w >> 1) : ((BM == 64 || BN == 128) ? (w & 1) : 0);
    const int mbase = M64N128 ? wm * 32
                     : ((BM == 64) ? wm * 32 : ((BN == 128) ? wm * 64 : w * 32));
    const int nbase = M64N128 ? wn * 64
                     : ((BM == 64) ? wn * 32 : ((BN == 128) ? wn * 64 : 0));
    const int JA = BM / 32;                      // A stage gloads per wave
    const int JB = BN / 32;

    floatx4 acc[4][4];
    #pragma unroll
    for (int i = 0; i < 4; i++)
        #pragma unroll
        for (int j = 0; j < 4; j++)
            acc[i][j] = (floatx4){0.f, 0.f, 0.f, 0.f};

    for (int k0 = 0; k0 < K; k0 += 64){
        __syncthreads();
        #pragma unroll
        for (int j = 0; j < JA; j++){
            int mrow = m0 + w * (BM / 4) + j * 8 + srow8;
            const u16* ga;
            if (AMODE == 0){
                ga = A + (size_t)mrow * K + k0 + swzc;
            } else {
                int bb = mrow >> 11, t = mrow & (T_ - 1);
                int kc = k0 >> 8;
                int c = (k0 & 255) + swzc;        // swzc<64, k0%64==0 -> no 256-cross
                int t2 = t + kc - 1;
                ga = ((unsigned)t2 < (unsigned)T_)
                     ? A + ((size_t)(bb * T_ + t2)) * D_ + c : zbuf;
            }
            gload16(ga, &As[(w * (BM / 4) + j * 8) * 64]);
        }
        #pragma unroll
        for (int j = 0; j < JB; j++){
            const u16* gb = Bw + (size_t)(n0 + w * (BN / 4) + j * 8 + srow8) * K + k0 + swzc;
            gload16(gb, &Bs[(w * (BN / 4) + j * 8) * 64]);
        }
        __syncthreads();
        #pragma unroll
        for (int ks = 0; ks < 2; ks++){
            const int rc = (((ks << 2) + quad) ^ lsw) * 8;
            bhalf8 af[4], bfr[4];
            #pragma unroll
            for (int mi = 0; mi < MT; mi++)
                af[mi] = *(const bhalf8*)&As[(mbase + mi * 16 + ln15) * 64 + rc];
            #pragma unroll
            for (int ni = 0; ni < NT; ni++)
                bfr[ni] = *(const bhalf8*)&Bs[(nbase + ni * 16 + ln15) * 64 + rc];
            #pragma unroll
            for (int mi = 0; mi < MT; mi++)
                #pragma unroll
                for (int ni = 0; ni < NT; ni++)
                    acc[mi][ni] = __builtin_amdgcn_mfma_f32_16x16x32_bf16(
                        af[mi], bfr[ni], acc[mi][ni], 0, 0, 0);
        }
    }
    if (VOUT && n0 >= 512){
        // V-projection blocks: write transposed directly into vbT layout.
        #pragma unroll
        for (int mi = 0; mi < MT; mi++){
            #pragma unroll
            for (int ni = 0; ni < NT; ni++){
                int n = n0 + nbase + ni * 16 + ln15;
                float bv = BIAS ? bias[n] : 0.f;
                int mbeg = m0 + mbase + mi * 16 + quad * 4;   // 4 consecutive t
                int bb = mbeg >> 11, tt = mbeg & (T_ - 1);
                u16 o4[4];
                #pragma unroll
                for (int r = 0; r < 4; r++) o4[r] = f2b(acc[mi][ni][r] + bv);
                *(ushort4*)(Cv + ((size_t)(bb * 256 + (n - 512))) * T_ + tt) = *(ushort4*)o4;
            }
        }
        return;
    }
    #pragma unroll
    for (int mi = 0; mi < MT; mi++){
        #pragma unroll
        for (int ni = 0; ni < NT; ni++){
            int n = n0 + nbase + ni * 16 + ln15;
            float bv = BIAS ? bias[n] : 0.f;
            #pragma unroll
            for (int r = 0; r < 4; r++){
                int m = m0 + mbase + mi * 16 + quad * 4 + r;
                float val = acc[mi][ni][r] + bv;
                if (ACT) val = lrelu(val);
                if (RES) val = res[(size_t)m * N + n] + alpha * val;
                if (OUTBF) ((u16*)C)[(size_t)m * N + n] = f2b(val);
                else       ((float*)C)[(size_t)m * N + n] = val;
            }
        }
    }
}

// ========== 8-wave QBLK=128 flash attention, gload_lds staging + XOR swizzle ==========
// (round-4..21 HW-verified structure; Op partials stored bf16, merge math f32)
__global__ __launch_bounds__(512) void attn11_kernel(
        const u16* __restrict__ qkv, const u16* __restrict__ vbT,
        const u16* __restrict__ posb,
        const float* __restrict__ ub, const float* __restrict__ vbias,
        u16* __restrict__ Op, float* __restrict__ ml,
        const u16* __restrict__ zbuf)
{
    __shared__ __align__(16) u16 Ks[64 * 64];
    __shared__ __align__(16) u16 Vs[64 * 64];
    __shared__ __align__(16) u16 Pos[192 * 64];
    __shared__ __align__(16) u16 Pb[8 * 16 * 90];

    const int tid = threadIdx.x;
    const int lane = tid & 63, w = tid >> 6;
    const int ln15 = lane & 15, quad = lane >> 4;
    const int lsw = ln15 & 7;                 // read-side XOR key (row&7 == ln15&7)

    // XCD-locality swizzle: 512 = 8 xcd * 2 bh * 2 z * 16 t-blocks (bijective)
    int wgid = blockIdx.x + 16 * (blockIdx.y + 16 * blockIdx.z);
    int xcd = wgid & 7, idx = wgid >> 3;               // idx in [0,64)
    const int bh = xcd * 2 + (idx >> 5);
    const int z  = (idx >> 4) & 1;
    const int t0 = (idx & 15) * 128;
    const int b = bh >> 2, h = bh & 3;

    const u16* qg  = qkv + (size_t)b * T_ * 768 + h * DH_;
    const u16* kg  = qkv + (size_t)b * T_ * 768 + 256 + h * DH_;
    const u16* vtg = vbT + ((size_t)(b * 256 + h * DH_)) * T_;
    const u16* pg  = posb + h * DH_;

    // staging geometry: wave w stages rows [w*8, w*8+8); lane -> (row, chunk)
    const int srow8 = lane >> 3;              // row within the wave's 8-row strip
    const int swz8  = (lane & 7) ^ srow8;     // pre-swizzled source chunk * 8 u16
    const int srowg = w * 8 + srow8;          // row within 64-row tile

    // ---- register Q fragments (wave w owns q-rows t0+w*16 .. +15) ----
    bhalf8 quf[2], qvf0[2], qvf1[2];
    {
        int qrow = t0 + w * 16 + ln15;
        #pragma unroll
        for (int ks = 0; ks < 2; ks++){
            int dof = ks * 32 + quad * 8;
            u16 q8[8];
            *(float4*)q8 = *(const float4*)(qg + (size_t)qrow * 768 + dof);
            u16 q8n[8] = {0,0,0,0,0,0,0,0};
            if (qrow + 1 < T_)
                *(float4*)q8n = *(const float4*)(qg + (size_t)(qrow + 1) * 768 + dof);
            u16 a[8], c0[8], c1[8];
            #pragma unroll
            for (int j = 0; j < 8; j++){
                float uu = ub[h * DH_ + dof + j];
                float vv = vbias[h * DH_ + dof + j];
                float qf = b2f(q8[j]), qf1 = b2f(q8n[j]);
                a[j]  = f2b(qf + uu);
                c0[j] = f2b(qf + vv);
                c1[j] = f2b(qf1 + vv);
            }
            quf[ks]  = *(bhalf8*)a;
            qvf0[ks] = *(bhalf8*)c0;
            qvf1[ks] = *(bhalf8*)c1;
        }
    }

    floatx4 O[4];
    #pragma unroll
    for (int i = 0; i < 4; i++) O[i] = (floatx4){0.f,0.f,0.f,0.f};
    float m_r[4], l_r[4];
    #pragma unroll
    for (int r = 0; r < 4; r++){ m_r[r] = -INFINITY; l_r[r] = 0.f; }

    u16* pbw = Pb + w * 16 * 90;
    const int prow0 = (7 - w) * 16 + ln15;   // band row base (127-offset space)

    int s0 = z * (T_ / 2);
    for (int it = 0; it < 16; it++, s0 += 64){
        const int diff = s0 - t0;
        __syncthreads();   // barrier 1: previous tile fully consumed
        // ---- stage K, V, Pos via global_load_lds (pre-swizzled source) ----
        {
            gload16(kg + (size_t)(s0 + srowg) * 768 + swz8 * 8, &Ks[(w * 8) * 64]);
            gload16(vtg + (size_t)srowg * T_ + s0 + swz8 * 8,  &Vs[(w * 8) * 64]);
            int jb = (diff <= 64) ? (T_ - 128 + diff) : (diff - 129);
            #pragma unroll
            for (int j = 0; j < 3; j++){
                int jj = jb + j * 64 + srowg;
                const u16* ga = ((unsigned)jj < (unsigned)T_)
                                ? pg + (size_t)jj * D_ + swz8 * 8 : zbuf;
                gload16(ga, &Pos[(j * 64 + w * 8) * 64]);
            }
        }
        __syncthreads();   // barrier 2: tile ready (barrier drains vmcnt)

        // ---- band first (keeps Bacc/S from being co-live) ----
        floatx4 Bacc[5];
        #pragma unroll
        for (int i = 0; i < 5; i++) Bacc[i] = (floatx4){0.f,0.f,0.f,0.f};
        #pragma unroll
        for (int ks = 0; ks < 2; ks++){
            bhalf8 av = (diff <= 64) ? qvf0[ks] : qvf1[ks];
            #pragma unroll
            for (int n5 = 0; n5 < 5; n5++){
                bhalf8 bf = *(const bhalf8*)&Pos[(prow0 + n5 * 16) * 64
                                                 + (((ks << 2) + quad) ^ lsw) * 8];
                Bacc[n5] = __builtin_amdgcn_mfma_f32_16x16x32_bf16(av, bf, Bacc[n5], 0, 0, 0);
            }
        }
        if (diff == 0 || diff == 64){
            // mixed diagonal tile: s>t half via direct-global pos fragments
            int jb2 = diff - 129;
            #pragma unroll
            for (int ks = 0; ks < 2; ks++){
                #pragma unroll
                for (int n5 = 0; n5 < 5; n5++){
                    int jj = jb2 + prow0 + n5 * 16;
                    const u16* pp = ((unsigned)jj < (unsigned)T_)
                        ? pg + (size_t)jj * D_ + ks * 32 + quad * 8 : zbuf;
                    Bacc[n5] = __builtin_amdgcn_mfma_f32_16x16x32_bf16(qvf1[ks], *(const bhalf8*)pp,
                                                                       Bacc[n5], 0, 0, 0);
                }
            }
        }
        // ---- wave-local band strip write (Bacc dies here) ----
        #pragma unroll
        for (int n5 = 0; n5 < 5; n5++)
            #pragma unroll
            for (int r = 0; r < 4; r++)
                pbw[(quad * 4 + r) * 90 + n5 * 16 + ln15] = f2b(Bacc[n5][r]);

        // ---- QK ----
        floatx4 S[4];
        #pragma unroll
        for (int i = 0; i < 4; i++) S[i] = (floatx4){0.f,0.f,0.f,0.f};
        #pragma unroll
        for (int ks = 0; ks < 2; ks++){
            #pragma unroll
            for (int nt = 0; nt < 4; nt++){
                bhalf8 bf = *(const bhalf8*)&Ks[(nt * 16 + ln15) * 64
                                                + (((ks << 2) + quad) ^ lsw) * 8];
                S[nt] = __builtin_amdgcn_mfma_f32_16x16x32_bf16(quf[ks], bf, S[nt], 0, 0, 0);
            }
        }
        // ---- shifted band read + score ----
        float sc[4][4];
        #pragma unroll
        for (int nt = 0; nt < 4; nt++)
            #pragma unroll
            for (int r = 0; r < 4; r++){
                int i = quad * 4 + r;
                int c = nt * 16 + ln15 + 15 - i;
                sc[nt][r] = (S[nt][r] + b2f(pbw[i * 90 + c])) * 0.0625f;
            }
        // ---- online softmax (__expf), DPP reductions ----
        #pragma unroll
        for (int r = 0; r < 4; r++){
            float rowm = fmaxf(fmaxf(sc[0][r], sc[1][r]), fmaxf(sc[2][r], sc[3][r]));
            rowm = dpp16_max(rowm);
            float mnew = fmaxf(m_r[r], rowm);
            float alpha = __expf(m_r[r] - mnew);
            float rs = 0.f;
            #pragma unroll
            for (int nt = 0; nt < 4; nt++){ sc[nt][r] = __expf(sc[nt][r] - mnew); rs += sc[nt][r]; }
            rs = dpp16_add(rs);
            l_r[r] = l_r[r] * alpha + rs;
            m_r[r] = mnew;
            O[0][r] *= alpha; O[1][r] *= alpha; O[2][r] *= alpha; O[3][r] *= alpha;
        }
        #pragma unroll
        for (int nt = 0; nt < 4; nt++)
            #pragma unroll
            for (int r = 0; r < 4; r++)
                pbw[(quad * 4 + r) * 90 + nt * 16 + ln15] = f2b(sc[nt][r]);
        // ---- PV (strip is wave-private: no barrier needed) ----
        #pragma unroll
        for (int ks = 0; ks < 2; ks++){
            bhalf8 af = *(const bhalf8*)&pbw[ln15 * 90 + ks * 32 + quad * 8];
            #pragma unroll
            for (int nt = 0; nt < 4; nt++){
                bhalf8 bf = *(const bhalf8*)&Vs[(nt * 16 + ln15) * 64
                                                + (((ks << 2) + quad) ^ lsw) * 8];
                O[nt] = __builtin_amdgcn_mfma_f32_16x16x32_bf16(af, bf, O[nt], 0, 0, 0);
            }
        }
    }
    #pragma unroll
    for (int r = 0; r < 4; r++){
        int t = t0 + w * 16 + quad * 4 + r;
        size_t row = (size_t)(z * 32768 + bh * 2048 + t);
        #pragma unroll
        for (int nt = 0; nt < 4; nt++)
            Op[row * 64 + nt * 16 + ln15] = f2b(O[nt][r]);
        if (ln15 == 0){
            ml[row * 2 + 0] = m_r[r];
            ml[row * 2 + 1] = l_r[r];
        }
    }
}

// ------ merge split-K attention partials (bf16 partials, f32 math, 8/thread) ------
__global__ __launch_bounds__(256) void amerge_kernel(const u16* __restrict__ Op,
        const float* __restrict__ ml, u16* __restrict__ ctx){
    int gid = blockIdx.x * 256 + threadIdx.x;
    int row = gid >> 3, d8 = (gid & 7) * 8;
    int bh = row >> 11, t = row & 2047;
    int b = bh >> 2, h = bh & 3;
    float m1 = ml[(size_t)row * 2], l1 = ml[(size_t)row * 2 + 1];
    float m2 = ml[(size_t)(32768 + row) * 2], l2 = ml[(size_t)(32768 + row) * 2 + 1];
    float m = fmaxf(m1, m2);
    float a1 = __expf(m1 - m), a2 = __expf(m2 - m);
    float invl = 1.f / (l1 * a1 + l2 * a2);
    u16 p1[8], p2[8], o8[8];
    *(float4*)p1 = *(const float4*)(Op + (size_t)row * 64 + d8);
    *(float4*)p2 = *(const float4*)(Op + (size_t)(32768 + row) * 64 + d8);
    #pragma unroll
    for (int j = 0; j < 8; j++)
        o8[j] = f2b((b2f(p1[j]) * a1 + b2f(p2[j]) * a2) * invl);
    *(float4*)(ctx + ((size_t)(b * T_ + t)) * D_ + h * DH_ + d8) = *(float4*)o8;
}

// ------- depthwise conv K=7, fused GLU tile-load, wave-reduced GN stats -------
#define TT_ 32
__global__ __launch_bounds__(256) void dw2_kernel(const u16* __restrict__ ypw1,
        const float* __restrict__ w, const float* __restrict__ bias,
        u16* __restrict__ y, float* __restrict__ stats){
    __shared__ u16 tile[(TT_ + 6) * INNER_];
    int tid = threadIdx.x;
    int t0 = blockIdx.x * TT_, b = blockIdx.y;
    for (int uu = tid; uu < (TT_ + 6) * 64; uu += 256){
        int row = uu >> 6, c8 = (uu & 63) * 8;
        int t = t0 + row - 3;
        u16 o8[8] = {0,0,0,0,0,0,0,0};
        if ((unsigned)t < (unsigned)T_){
            u16 a8[8], g8[8];
            const u16* rp = ypw1 + ((size_t)(b * T_ + t)) * 1024;
            *(float4*)a8 = *(const float4*)(rp + c8);
            *(float4*)g8 = *(const float4*)(rp + 512 + c8);
            #pragma unroll
            for (int j = 0; j < 8; j++) o8[j] = f2b(b2f(a8[j]) * lrelu(b2f(g8[j])));
        }
        *(float4*)&tile[row * INNER_ + c8] = *(float4*)o8;
    }
    __syncthreads();
    int c8 = (tid & 63) * 8, trow = tid >> 6;
    float wreg[7][8], bv[8];
    #pragma unroll
    for (int j = 0; j < 8; j++){
        bv[j] = bias[c8 + j];
        #pragma unroll
        for (int kk = 0; kk < 7; kk++) wreg[kk][j] = w[(c8 + j) * 7 + kk];
    }
    float s1 = 0.f, s2 = 0.f;
    for (int tt = trow; tt < TT_; tt += 4){
        float acc[8];
        #pragma unroll
        for (int j = 0; j < 8; j++) acc[j] = bv[j];
        #pragma unroll
        for (int kk = 0; kk < 7; kk++){
            u16 r8[8];
            *(float4*)r8 = *(const float4*)&tile[(tt + kk) * INNER_ + c8];
            #pragma unroll
            for (int j = 0; j < 8; j++) acc[j] += b2f(r8[j]) * wreg[kk][j];
        }
        u16 o8[8];
        #pragma unroll
        for (int j = 0; j < 8; j++) o8[j] = f2b(acc[j]);
        *(float4*)(y + ((size_t)(b * T_ + t0 + tt)) * INNER_ + c8) = *(float4*)o8;
        #pragma unroll
        for (int j = 0; j < 8; j++){ s1 += acc[j]; s2 += acc[j] * acc[j]; }
    }
    #pragma unroll
    for (int mk = 1; mk < 64; mk <<= 1){
        s1 += __shfl_xor(s1, mk, 64);
        s2 += __shfl_xor(s2, mk, 64);
    }
    if ((tid & 63) == 0){
        atomicAdd(&stats[b * 2], s1);
        atomicAdd(&stats[b * 2 + 1], s2);
    }
}

// ---------------- GroupNorm(1) apply + leaky, bf16 in/out ----------------
__global__ __launch_bounds__(256) void gn_kernel(const u16* __restrict__ y,
        const float* __restrict__ g, const float* __restrict__ b2,
        const float* __restrict__ stats, u16* __restrict__ out){
    int idx8 = (blockIdx.x * 256 + threadIdx.x) * 8;
    int b = idx8 / (T_ * INNER_);
    int i = idx8 & (INNER_ - 1);
    const float invN = 1.f / (float)(T_ * INNER_);
    float mean = stats[b * 2] * invN;
    float var  = stats[b * 2 + 1] * invN - mean * mean;
    float rs = rsqrtf(var + 1e-5f);
    u16 v8[8], o8[8];
    *(float4*)v8 = *(const float4*)(y + idx8);
    #pragma unroll
    for (int j = 0; j < 8; j++)
        o8[j] = f2b(lrelu((b2f(v8[j]) - mean) * rs * g[i + j] + b2[i + j]));
    *(float4*)(out + idx8) = *(float4*)o8;
}

extern "C" void kernel_launch(void* const* d_in, const int* in_sizes, int n_in,
                              void* d_out, int out_size, void* d_ws, size_t ws_size,
                              hipStream_t stream){
    const float* x        = (const float*)d_in[0];
    const float* enc      = (const float*)d_in[1];
    const float* ff_ln_g  = (const float*)d_in[3];
    const float* ff_ln_b  = (const float*)d_in[4];
    const float* ff_w1    = (const float*)d_in[5];
    const float* ff_b1    = (const float*)d_in[6];
    const float* ff_w2    = (const float*)d_in[7];
    const float* ff_b2    = (const float*)d_in[8];
    const float* at_ln_g  = (const float*)d_in[9];
    const float* at_ln_b  = (const float*)d_in[10];
    const float* q_w      = (const float*)d_in[11];
    const float* q_b      = (const float*)d_in[12];
    const float* k_w      = (const float*)d_in[13];
    const float* v_w      = (const float*)d_in[14];
    const float* pos_w    = (const float*)d_in[15];
    const float* u_bias   = (const float*)d_in[16];
    const float* v_bias   = (const float*)d_in[17];
    const float* out_w    = (const float*)d_in[18];
    const float* out_b    = (const float*)d_in[19];
    const float* cm_ln_g  = (const float*)d_in[20];
    const float* cm_ln_b  = (const float*)d_in[21];
    const float* pw1_w    = (const float*)d_in[22];
    const float* pw1_b    = (const float*)d_in[23];
    const float* dw_w     = (const float*)d_in[24];
    const float* dw_b     = (const float*)d_in[25];
    const float* gn_g     = (const float*)d_in[26];
    const float* gn_b     = (const float*)d_in[27];
    const float* pw2_w    = (const float*)d_in[28];
    const float* pw2_b    = (const float*)d_in[29];
    float* out = (float*)d_out;

    char* ws = (char*)d_ws;
    u16*   y1bf = (u16*)(ws + 0);
    u16*   ypw1 = (u16*)(ws + 0);
    u16*   Op   = (u16*)(ws + 0);
    float* ml   = (float*)(ws + ((size_t)16 << 20));
    u16*   ydw  = (u16*)(ws + ((size_t)16 << 20));
    u16*   qkv  = (u16*)(ws + ((size_t)32 << 20));
    u16*   vbT  = (u16*)(ws + ((size_t)44 << 20));
    u16*   ctxb = (u16*)(ws + ((size_t)48 << 20));
    u16*   posb = (u16*)(ws + ((size_t)52 << 20));
    u16*   lnbuf= (u16*)(ws + ((size_t)53 << 20));
    float* x1   = (float*)(ws + ((size_t)57 << 20));
    float* x2   = (float*)(ws + ((size_t)65 << 20));
    u16*   gnb  = (u16*)(ws + ((size_t)36 << 20));
    char* W = ws + ((size_t)81 << 20);
    u16* ff1w  = (u16*)(W);
    u16* ff2w  = (u16*)(W + ((size_t)2 << 20));
    u16* qkvw  = (u16*)(W + ((size_t)3 << 20));
    u16* kw    = qkvw + 65536;
    u16* vw    = qkvw + 131072;
    u16* posw  = (u16*)(W + ((size_t)3 << 20) + (384u << 10));
    u16* outw  = (u16*)(W + ((size_t)4 << 20));
    u16* pw1w  = (u16*)(W + ((size_t)5 << 20));
    u16* pw2w  = (u16*)(W + ((size_t)6 << 20));
    u16* encb  = (u16*)(W + ((size_t)7 << 20));
    u16* zbuf  = (u16*)(W + ((size_t)8 << 20));
    float* stats    = (float*)(W + ((size_t)8 << 20) + 4096);
    float* qkv_bias = (float*)(W + ((size_t)8 << 20) + 8192);

    const int MBT = B_ * T_;

    hipMemsetAsync(W + ((size_t)8 << 20), 0, 16384, stream);
    hipMemcpyAsync(qkv_bias, q_b, 256 * sizeof(float), hipMemcpyDeviceToDevice, stream);
    cast4_kernel<<<dim3(512, 4), 256, 0, stream>>>(
        ff_w2, ff2w, 256*1024, pw1_w, pw1w, 1024*256,
        pw2_w, pw2w, 256*512,  enc,   encb, 2048*256);
    castT5_kernel<<<dim3(16, 5), 256, 0, stream>>>(
        q_w, k_w, v_w, pos_w, out_w, qkvw, kw, vw, posw, outw);
    castFF1_kernel<<<3072, 256, 0, stream>>>(ff_w1, ff1w);

    // --- FeedForward ---
    ln_kernel<<<MBT/4, 256, 0, stream>>>(x, ff_ln_g, ff_ln_b, lnbuf);
    gemm_bf<64,128,1,true,true,false,true,false><<<dim3(FFI_/128, MBT/64), 256, 0, stream>>>(
        lnbuf, ff1w, ff_b1, nullptr, y1bf, MBT, FFI_, 3*D_, 0.f, zbuf, nullptr);
    gemm_bf<64,64,0,true,false,true,false,false><<<dim3(D_/64, MBT/64), 256, 0, stream>>>(
        y1bf, ff2w, ff_b2, x, x1, MBT, D_, FFI_, 0.5f, nullptr, nullptr);

    // --- Relative MHSA ---
    ln_kernel<<<MBT/4, 256, 0, stream>>>(x1, at_ln_g, at_ln_b, lnbuf);
    gemm_bf<128,64,0,true,false,false,true,true><<<dim3(768/64, MBT/128), 256, 0, stream>>>(
        lnbuf, qkvw, qkv_bias, nullptr, qkv, MBT, 768, D_, 0.f, nullptr, vbT);
    gemm_bf<128,64,0,false,false,false,true,false><<<dim3(D_/64, T_/128), 256, 0, stream>>>(
        encb, posw, nullptr, nullptr, posb, T_, D_, D_, 0.f, nullptr, nullptr);
    attn11_kernel<<<dim3(T_/128, B_*H_, 2), 512, 0, stream>>>(
        qkv, vbT, posb, u_bias, v_bias, Op, ml, zbuf);
    amerge_kernel<<<(32768 * 8) / 256, 256, 0, stream>>>(Op, ml, ctxb);
    gemm_bf<64,64,0,true,false,true,false,false><<<dim3(D_/64, MBT/64), 256, 0, stream>>>(
        ctxb, outw, out_b, x1, x2, MBT, D_, D_, 1.f, nullptr, nullptr);

    // --- Conformer conv module ---
    ln_kernel<<<MBT/4, 256, 0, stream>>>(x2, cm_ln_g, cm_ln_b, lnbuf);
    gemm_bf<64,128,0,true,false,false,true,false><<<dim3(FFI_/128, MBT/64), 256, 0, stream>>>(
        lnbuf, pw1w, pw1_b, nullptr, ypw1, MBT, FFI_, D_, 0.f, nullptr, nullptr);
    dw2_kernel<<<dim3(T_/TT_, B_), 256, 0, stream>>>(ypw1, dw_w, dw_b, ydw, stats);
    gn_kernel<<<(MBT * INNER_) / (256 * 8), 256, 0, stream>>>(ydw, gn_g, gn_b, stats, gnb);
    gemm_bf<64,64,0,true,false,true,false,false><<<dim3(D_/64, MBT/64), 256, 0, stream>>>(
        gnb, pw2w, pw2_b, x2, out, MBT, D_, INNER_, 1.f, nullptr, nullptr);
}